// Round 3
// baseline (121.205 us; speedup 1.0000x reference)
//
#include <hip/hip_runtime.h>
#include <math.h>

typedef __attribute__((ext_vector_type(8))) short bf16x8;   // 8 bf16 (4 VGPRs)
typedef __attribute__((ext_vector_type(4))) float f32x4;    // MFMA acc

#define SQRT3F     1.7320508075688772f
#define SCALE_T    0.17677669529663687f    // 1/sqrt(32)
#define SCALE_M1   0.025515518153991442f   // C_SCALAR/sqrt(32)
#define SCALE_M2   0.014731391274719739f   // C_SCALAR*inv_sqrt3/sqrt(32)
#define SCALE_M34  0.036084391824351615f   // C_SCALAR/4

#define FSTR 40    // feature row stride (shorts): 80 B
#define ASTR 72    // agg row stride (shorts): 144 B (16B-aligned, bank-spread)

__device__ __forceinline__ ushort f2bf(float f) {
    union { float f; unsigned u; } v; v.f = f;
    unsigned u = v.u;
    return (ushort)((u + 0x7FFFu + ((u >> 16) & 1u)) >> 16);
}
__device__ __forceinline__ float bf2f(ushort h) {
    union { unsigned u; float f; } v; v.u = ((unsigned)h) << 16;
    return v.f;
}
__device__ __forceinline__ f32x4 mfma(bf16x8 a, bf16x8 b, f32x4 c) {
    return __builtin_amdgcn_mfma_f32_16x16x32_bf16(a, b, c, 0, 0, 0);
}
// stage-1 D-tile -> agg[n][u0..u0+3] (4 consecutive u), bf16 packed
__device__ __forceinline__ void storeAgg(ushort* AG, f32x4 t, int u0, int n) {
    uint2 u;
    u.x = f2bf(t[0]) | ((unsigned)f2bf(t[1]) << 16);
    u.y = f2bf(t[2]) | ((unsigned)f2bf(t[3]) << 16);
    *(uint2*)&AG[n*ASTR + u0] = u;
}
// residual + relu RMW of 4 consecutive nodes at channel c (packed uint2)
__device__ __forceinline__ void rmw4(ushort* F, int c, int n0, f32x4 h) {
    uint2* p = (uint2*)&F[c*FSTR + n0];
    uint2 o = *p;
    float f0 = bf2f((ushort)(o.x      )) + fmaxf(h[0], 0.f);
    float f1 = bf2f((ushort)(o.x >> 16)) + fmaxf(h[1], 0.f);
    float f2 = bf2f((ushort)(o.y      )) + fmaxf(h[2], 0.f);
    float f3 = bf2f((ushort)(o.y >> 16)) + fmaxf(h[3], 0.f);
    uint2 w;
    w.x = f2bf(f0) | ((unsigned)f2bf(f1) << 16);
    w.y = f2bf(f2) | ((unsigned)f2bf(f3) << 16);
    *p = w;
}
// XOR-swizzled Mlds address: flat row in [0,144), col in shorts [0,64).
// Row stride 128 B -> (row&7)<<4 XOR spreads 16-row frag reads over 8 bank
// quads (2-way = free). 16B alignment preserved (XOR bits 4..6 only).
__device__ __forceinline__ char* mlPtr(char* ML, int row, int colS) {
    return ML + (((row * 128) + colS * 2) ^ ((row & 7) << 4));
}

// ---------------------------------------------------------------------------
// Single fused kernel: in-kernel weight fold (replaces prep kernel) +
// GNN layers + MLP head. One wave = one graph; 4 graphs/block; 512 blocks
// (all co-resident at 2 blocks/CU; LDS 63.7 KB).
// Fold: Mlds[lay][48][64] bf16 = products of per-layer weight matrices,
// computed by 27 MFMA tiles split across the block's 4 waves (coalesced
// operand loads -> no TA serialization, unlike the old scalar fold).
// s-init: emb[z] @ W_s2n via 4 MFMAs per wave (drops Tbf + prep entirely).
// ---------------------------------------------------------------------------
__global__ __launch_bounds__(256)
void gnn_kernel(const float* __restrict__ pos, const int* __restrict__ z,
                const float* __restrict__ emb, const float* __restrict__ W_s2n,
                const float* __restrict__ W1, const float* __restrict__ W2,
                const float* __restrict__ W3, const float* __restrict__ W4,
                const float* __restrict__ Ws, const float* __restrict__ Wv,
                const float* __restrict__ Wr1, const float* __restrict__ br1,
                const float* __restrict__ Wr2, const float* __restrict__ br2,
                float* __restrict__ out)
{
    __shared__ __align__(16) char smem[63744];
    ushort* featA = (ushort*)smem;                    // 4*80*40*2 = 25600 B
    ushort* aggA  = (ushort*)(smem + 25600);          // 4*32*72*2 = 18432 B
    char*   MLb   = smem + 44032;                     // 144*64*2  = 18432 B (swizzled)
    float*  hgl   = (float*)(smem + 62464);           // 4*80*4    = 1280 B
    float*  h1    = (float*)aggA;                     // alias (post-layers)
    float*  red   = ((float*)aggA) + 1024;            // alias, +4096 B

    const int tid = threadIdx.x;
    const int wv = tid >> 6, l = tid & 63;
    const int g  = blockIdx.x*4 + wv;
    ushort* F  = featA + wv*80*FSTR;
    ushort* AG = aggA  + wv*32*ASTR;
    const int ln = l & 15, kq = l >> 4;
    const f32x4 z4 = {0.f, 0.f, 0.f, 0.f};

    // zero agg (incl. K-pad cols 48..63) and v feature rows (wave-private)
    for (int i = l; i < 32*(ASTR/2); i += 64) ((uint*)AG)[i] = 0;
    for (int i = l; i < 48*(FSTR/2); i += 64) ((uint*)(F + 32*FSTR))[i] = 0;
    // zero Mlds K-pad cols 48..63 (block-shared; consumed by kc=1,kq>=2 frags)
    for (int i = tid; i < 144*8; i += 256) {
        int row = i >> 3, c = i & 7;
        *(uint*)(MLb + (((row*128) + 96 + c*4) ^ ((row & 7) << 4))) = 0;
    }

    // ---- in-kernel M fold: 27 MFMA tiles (9/layer) split across 4 waves.
    // D[w][u] per tile; A[w][k], B[k][u] built from raw weights (scales on B).
    for (int t = wv; t < 27; t += 4) {
        int lay = t / 9, rr = t - lay*9;
        union { bf16x8 v; ushort s[8]; } af, bfv;
        int w0, u0;
        if (rr < 6) {                                  // scalar-out region w<32
            w0 = (rr & 1)*16; u0 = (rr >> 1)*16;
            #pragma unroll
            for (int e = 0; e < 8; ++e)                // A[w][k] = Ws[k][w]
                af.s[e] = f2bf(Ws[lay*1024 + (kq*8+e)*32 + w0 + ln]);
            if (u0 < 32) {                             // B[k][u] = S1*W1[u][k]
                const float* src = W1 + lay*1024 + (u0+ln)*32 + kq*8;
                #pragma unroll
                for (int e = 0; e < 8; ++e) bfv.s[e] = f2bf(src[e] * SCALE_M1);
            } else {                                   // B[k][u] = S2*W4[u-32][k]
                const float* src = W4 + lay*512 + ln*32 + kq*8;
                #pragma unroll
                for (int e = 0; e < 8; ++e) bfv.s[e] = f2bf(src[e] * SCALE_M2);
            }
        } else {                                       // vector-out region w in [32,48)
            w0 = 32; u0 = (rr - 6)*16;
            #pragma unroll
            for (int e = 0; e < 8; ++e) {              // A[w'][k] = Wv[k][w'], K=16
                int k = kq*8 + e;
                af.s[e] = (k < 16) ? f2bf(Wv[lay*256 + k*16 + ln]) : (ushort)0;
            }
            if (u0 < 32) {                             // B = S34*W2[u][k], K=16
                #pragma unroll
                for (int e = 0; e < 8; ++e) {
                    int k = kq*8 + e;
                    float x = (k < 16) ? W2[lay*512 + (u0+ln)*16 + k] : 0.f;
                    bfv.s[e] = f2bf(x * SCALE_M34);
                }
            } else {                                   // B = S34*W3[u-32][k], K=16
                #pragma unroll
                for (int e = 0; e < 8; ++e) {
                    int k = kq*8 + e;
                    float x = (k < 16) ? W3[lay*256 + ln*16 + k] : 0.f;
                    bfv.s[e] = f2bf(x * SCALE_M34);
                }
            }
        }
        f32x4 d = mfma(af.v, bfv.v, z4);
        #pragma unroll
        for (int q = 0; q < 4; ++q) {
            int row = lay*48 + w0 + kq*4 + q;
            *(ushort*)mlPtr(MLb, row, u0 + ln) = f2bf(d[q]);
        }
    }

    // ---- s init via MFMA: F[c][n] = (emb[z[n]] @ W_s2n)[c] * SCALE_T
    {
        union { bf16x8 v; ushort s[8]; } aT[2], bE[2];
        #pragma unroll
        for (int c = 0; c < 2; ++c)                    // A[c][k] = ST*W_s2n[k][c]
            #pragma unroll
            for (int e = 0; e < 8; ++e)
                aT[c].s[e] = f2bf(W_s2n[(kq*8+e)*32 + c*16 + ln] * SCALE_T);
        #pragma unroll
        for (int n = 0; n < 2; ++n) {                  // B[k][n] = emb[z[n]][k]
            int zz = z[g*32 + n*16 + ln];
            const float* er = emb + zz*32 + kq*8;
            float4 e0 = *(const float4*)er, e1 = *(const float4*)(er + 4);
            bE[n].s[0] = f2bf(e0.x); bE[n].s[1] = f2bf(e0.y);
            bE[n].s[2] = f2bf(e0.z); bE[n].s[3] = f2bf(e0.w);
            bE[n].s[4] = f2bf(e1.x); bE[n].s[5] = f2bf(e1.y);
            bE[n].s[6] = f2bf(e1.z); bE[n].s[7] = f2bf(e1.w);
        }
        #pragma unroll
        for (int c = 0; c < 2; ++c)
            #pragma unroll
            for (int n = 0; n < 2; ++n) {
                f32x4 d = mfma(aT[c].v, bE[n].v, z4);
                #pragma unroll
                for (int q = 0; q < 4; ++q)
                    F[(c*16 + kq*4 + q)*FSTR + n*16 + ln] = f2bf(d[q]);
            }
    }

    // adjacency fragments inline (layer-invariant, 32 VGPRs)
    bf16x8 adjf[4][2];
    {
        const int k0 = kq*8;
        #pragma unroll
        for (int nt = 0; nt < 2; ++nt) {
            int ng = g*32 + nt*16 + ln;
            float px = pos[3*ng], py = pos[3*ng+1], pz = pos[3*ng+2];
            union { bf16x8 v; ushort s[8]; } o[4];
            #pragma unroll
            for (int jj = 0; jj < 8; ++jj) {
                int j = g*32 + k0 + jj;
                float dx = __fsub_rn(px, pos[3*j]);
                float dy = __fsub_rn(py, pos[3*j+1]);
                float dz = __fsub_rn(pz, pos[3*j+2]);
                float d2 = __fadd_rn(__fadd_rn(__fmul_rn(dx,dx), __fmul_rn(dy,dy)),
                                     __fmul_rn(dz,dz));
                bool on = (d2 <= 25.0f) && (d2 > 0.0f);
                float rinv = on ? rsqrtf(d2) * SQRT3F : 0.f;
                o[0].s[jj] = on ? (ushort)0x3F80 : (ushort)0;   // bf16(1.0)
                o[1].s[jj] = f2bf(dx * rinv);
                o[2].s[jj] = f2bf(dy * rinv);
                o[3].s[jj] = f2bf(dz * rinv);
            }
            #pragma unroll
            for (int w = 0; w < 4; ++w) adjf[w][nt] = o[w].v;
        }
    }

    __syncthreads();   // Mlds fold complete (F/AG are wave-private)

    for (int lay = 0; lay < 3; ++lay) {
        const int layRow = lay*48;
        // feature fragments (pre-update values)
        bf16x8 fs0 = *(const bf16x8*)&F[(     ln)*FSTR + kq*8];
        bf16x8 fs1 = *(const bf16x8*)&F[(16 + ln)*FSTR + kq*8];
        bf16x8 fv0 = *(const bf16x8*)&F[(32 + ln)*FSTR + kq*8];
        bf16x8 fv1 = *(const bf16x8*)&F[(48 + ln)*FSTR + kq*8];
        bf16x8 fv2 = *(const bf16x8*)&F[(64 + ln)*FSTR + kq*8];
        // M fragments for this layer (swizzled LDS)
        bf16x8 bmS0[2], bmS1[2], bmV[2];
        #pragma unroll
        for (int kc = 0; kc < 2; ++kc) {
            bmS0[kc] = *(const bf16x8*)mlPtr(MLb, layRow +      ln, kc*32 + kq*8);
            bmS1[kc] = *(const bf16x8*)mlPtr(MLb, layRow + 16 + ln, kc*32 + kq*8);
            bmV [kc] = *(const bf16x8*)mlPtr(MLb, layRow + 32 + ln, kc*32 + kq*8);
        }

        // ---- scalar path: agg = [A0 (u<32) | a3 (u 32..47)]
        #pragma unroll
        for (int nt = 0; nt < 2; ++nt) {
            f32x4 t;
            t = mfma(fs0, adjf[0][nt], z4);
            storeAgg(AG, t,      kq*4, nt*16 + ln);
            t = mfma(fs1, adjf[0][nt], z4);
            storeAgg(AG, t, 16 + kq*4, nt*16 + ln);
            t = mfma(fv2, adjf[3][nt], z4);
            t = mfma(fv1, adjf[2][nt], t);
            t = mfma(fv0, adjf[1][nt], t);
            storeAgg(AG, t, 32 + kq*4, nt*16 + ln);
        }
        f32x4 hs[2][2] = {{z4, z4}, {z4, z4}};   // [node-tile][w-tile]
        #pragma unroll
        for (int kc = 0; kc < 2; ++kc)
            #pragma unroll
            for (int mt = 0; mt < 2; ++mt) {
                bf16x8 ag = *(const bf16x8*)&AG[(mt*16 + ln)*ASTR + kc*32 + kq*8];
                hs[mt][0] = mfma(ag, bmS0[kc], hs[mt][0]);
                hs[mt][1] = mfma(ag, bmS1[kc], hs[mt][1]);
            }
        #pragma unroll
        for (int mt = 0; mt < 2; ++mt)
            #pragma unroll
            for (int wt = 0; wt < 2; ++wt)
                rmw4(F, wt*16 + ln, mt*16 + kq*4, hs[mt][wt]);

        // ---- vector path, one spatial component i at a time (reuses AG)
        #pragma unroll
        for (int i = 0; i < 3; ++i) {
            bf16x8 fvi = (i == 0) ? fv0 : (i == 1) ? fv1 : fv2;
            #pragma unroll
            for (int nt = 0; nt < 2; ++nt) {
                f32x4 t;
                t = mfma(fs0, adjf[1+i][nt], z4);
                storeAgg(AG, t,      kq*4, nt*16 + ln);
                t = mfma(fs1, adjf[1+i][nt], z4);
                storeAgg(AG, t, 16 + kq*4, nt*16 + ln);
                t = mfma(fvi, adjf[0][nt], z4);
                storeAgg(AG, t, 32 + kq*4, nt*16 + ln);
            }
            f32x4 hv[2] = {z4, z4};
            #pragma unroll
            for (int kc = 0; kc < 2; ++kc)
                #pragma unroll
                for (int mt = 0; mt < 2; ++mt) {
                    bf16x8 ag = *(const bf16x8*)&AG[(mt*16 + ln)*ASTR + kc*32 + kq*8];
                    hv[mt] = mfma(ag, bmV[kc], hv[mt]);
                }
            #pragma unroll
            for (int mt = 0; mt < 2; ++mt)
                rmw4(F, 32 + i*16 + ln, mt*16 + kq*4, hv[mt]);
        }
    }

    // wave-local sum-pool -> hgl[wv][80]
    for (int f = l; f < 80; f += 64) {
        const ushort* row;
        if (f < 32) row = &F[f*FSTR];
        else { int c = f - 32, w = c/3, i = c - 3*w; row = &F[(32 + i*16 + w)*FSTR]; }
        const uint* r32 = (const uint*)row;
        float acc = 0.f;
        #pragma unroll
        for (int q = 0; q < 16; ++q) {
            uint u = r32[q];
            acc += bf2f((ushort)u) + bf2f((ushort)(u >> 16));
        }
        hgl[wv*80 + f] = acc;
    }
    __syncthreads();   // all waves done; hgl complete; aggA free for h1 alias

    // --- fused MLP head (block = its 4 graphs) ---
    {
        const int w = tid;
        float acc0 = br1[w];
        float acc1 = acc0, acc2 = acc0, acc3 = acc0;
        #pragma unroll 4
        for (int f = 0; f < 80; ++f) {
            float wvv = Wr1[f*256 + w];
            acc0 = fmaf(hgl[0*80 + f], wvv, acc0);
            acc1 = fmaf(hgl[1*80 + f], wvv, acc1);
            acc2 = fmaf(hgl[2*80 + f], wvv, acc2);
            acc3 = fmaf(hgl[3*80 + f], wvv, acc3);
        }
        h1[0*256 + w] = fmaxf(acc0, 0.f);
        h1[1*256 + w] = fmaxf(acc1, 0.f);
        h1[2*256 + w] = fmaxf(acc2, 0.f);
        h1[3*256 + w] = fmaxf(acc3, 0.f);
    }
    __syncthreads();
    {
        const int g0 = blockIdx.x * 4;
        const int w2 = tid & 127, kh = tid >> 7;
        const float4* h1v = (const float4*)h1;   // [4][64] float4 view
        float s0 = 0.f, s1 = 0.f, s2 = 0.f, s3 = 0.f;
        #pragma unroll 2
        for (int k4 = kh*32; k4 < kh*32 + 32; ++k4) {
            float4 hA = h1v[0*64 + k4];
            float4 hB = h1v[1*64 + k4];
            float4 hC = h1v[2*64 + k4];
            float4 hD = h1v[3*64 + k4];
            int k = k4 * 4;
            float m0 = Wr2[(size_t)(k+0)*128 + w2];
            float m1 = Wr2[(size_t)(k+1)*128 + w2];
            float m2 = Wr2[(size_t)(k+2)*128 + w2];
            float m3 = Wr2[(size_t)(k+3)*128 + w2];
            s0 = fmaf(hA.x,m0, fmaf(hA.y,m1, fmaf(hA.z,m2, fmaf(hA.w,m3, s0))));
            s1 = fmaf(hB.x,m0, fmaf(hB.y,m1, fmaf(hB.z,m2, fmaf(hB.w,m3, s1))));
            s2 = fmaf(hC.x,m0, fmaf(hC.y,m1, fmaf(hC.z,m2, fmaf(hC.w,m3, s2))));
            s3 = fmaf(hD.x,m0, fmaf(hD.y,m1, fmaf(hD.z,m2, fmaf(hD.w,m3, s3))));
        }
        if (kh) {
            red[0*128 + w2] = s0; red[1*128 + w2] = s1;
            red[2*128 + w2] = s2; red[3*128 + w2] = s3;
        }
        __syncthreads();
        if (!kh) {
            float b = br2[w2];
            out[(size_t)(g0+0)*128 + w2] = s0 + red[0*128 + w2] + b;
            out[(size_t)(g0+1)*128 + w2] = s1 + red[1*128 + w2] + b;
            out[(size_t)(g0+2)*128 + w2] = s2 + red[2*128 + w2] + b;
            out[(size_t)(g0+3)*128 + w2] = s3 + red[3*128 + w2] + b;
        }
    }
}

// ---------------------------------------------------------------------------
extern "C" void kernel_launch(void* const* d_in, const int* in_sizes, int n_in,
                              void* d_out, int out_size, void* d_ws, size_t ws_size,
                              hipStream_t stream)
{
    const float* pos   = (const float*)d_in[0];
    const int*   z     = (const int*)d_in[1];
    const float* emb   = (const float*)d_in[5];
    const float* W_s2n = (const float*)d_in[6];
    const float* W1    = (const float*)d_in[7];
    const float* W2    = (const float*)d_in[8];
    const float* W3    = (const float*)d_in[9];
    const float* W4    = (const float*)d_in[10];
    const float* Ws    = (const float*)d_in[11];
    const float* Wv    = (const float*)d_in[12];
    const float* Wr1   = (const float*)d_in[13];
    const float* br1   = (const float*)d_in[14];
    const float* Wr2   = (const float*)d_in[15];
    const float* br2   = (const float*)d_in[16];
    float* out = (float*)d_out;

    const int B = out_size / 128;      // graphs (2048)

    // single fused launch; workspace unused (prep folded in-kernel)
    gnn_kernel<<<B / 4, 256, 0, stream>>>(pos, z, emb, W_s2n,
                                          W1, W2, W3, W4, Ws, Wv,
                                          Wr1, br1, Wr2, br2, out);
}

// Round 4
// 113.835 us; speedup vs baseline: 1.0647x; 1.0647x over previous
//
#include <hip/hip_runtime.h>
#include <math.h>

typedef __attribute__((ext_vector_type(8))) short bf16x8;   // 8 bf16 (4 VGPRs)
typedef __attribute__((ext_vector_type(4))) float f32x4;    // MFMA acc

#define SQRT3F     1.7320508075688772f
#define SCALE_T    0.17677669529663687f    // 1/sqrt(32)
#define SCALE_M1   0.025515518153991442f   // C_SCALAR/sqrt(32)
#define SCALE_M2   0.014731391274719739f   // C_SCALAR*inv_sqrt3/sqrt(32)
#define SCALE_M34  0.036084391824351615f   // C_SCALAR/4

#define FSTR 40    // feature row stride (shorts): 80 B
#define ASTR 72    // agg row stride (shorts): 144 B (16B-aligned, bank-spread)

__device__ __forceinline__ ushort f2bf(float f) {
    union { float f; unsigned u; } v; v.f = f;
    unsigned u = v.u;
    return (ushort)((u + 0x7FFFu + ((u >> 16) & 1u)) >> 16);
}
__device__ __forceinline__ float bf2f(ushort h) {
    union { unsigned u; float f; } v; v.u = ((unsigned)h) << 16;
    return v.f;
}
// single-instruction packed f32->bf16 (RNE), lo in [15:0], hi in [31:16].
// gfx950 has v_cvt_pk_bf16_f32 but no builtin (T12/m240) -> inline asm.
__device__ __forceinline__ unsigned cvtpk(float lo, float hi) {
    unsigned r;
    asm("v_cvt_pk_bf16_f32 %0, %1, %2" : "=v"(r) : "v"(lo), "v"(hi));
    return r;
}
__device__ __forceinline__ f32x4 mfma(bf16x8 a, bf16x8 b, f32x4 c) {
    return __builtin_amdgcn_mfma_f32_16x16x32_bf16(a, b, c, 0, 0, 0);
}
// stage-1 D-tile -> agg[n][u0..u0+3] (4 consecutive u), bf16 packed
__device__ __forceinline__ void storeAgg(ushort* AG, f32x4 t, int u0, int n) {
    uint2 u;
    u.x = cvtpk(t[0], t[1]);
    u.y = cvtpk(t[2], t[3]);
    *(uint2*)&AG[n*ASTR + u0] = u;
}
// residual + relu RMW of 4 consecutive nodes at channel c (packed uint2)
__device__ __forceinline__ void rmw4(ushort* F, int c, int n0, f32x4 h) {
    uint2* p = (uint2*)&F[c*FSTR + n0];
    uint2 o = *p;
    float f0 = bf2f((ushort)(o.x      )) + fmaxf(h[0], 0.f);
    float f1 = bf2f((ushort)(o.x >> 16)) + fmaxf(h[1], 0.f);
    float f2 = bf2f((ushort)(o.y      )) + fmaxf(h[2], 0.f);
    float f3 = bf2f((ushort)(o.y >> 16)) + fmaxf(h[3], 0.f);
    uint2 w;
    w.x = cvtpk(f0, f1);
    w.y = cvtpk(f2, f3);
    *p = w;
}

// ---------------------------------------------------------------------------
// Prep (tiny, one-shot): Tbf = bf16(emb@W_s2n * sT)  (100x32)
//   Mbf[lyr][row][64]: rows 0..31 = MsT[w][u], rows 32..47 = MvT[w][u],
//   cols 48..63 zero (K-pad). Executed ONCE — in-kernel block-redundant
//   folds regress (round-3: +18us from lost occupancy + cold-latency fold).
// ---------------------------------------------------------------------------
__global__ void prep_kernel(const float* __restrict__ emb,
                            const float* __restrict__ W_s2n,
                            const float* __restrict__ W1, const float* __restrict__ W2,
                            const float* __restrict__ W3, const float* __restrict__ W4,
                            const float* __restrict__ Ws, const float* __restrict__ Wv,
                            ushort* __restrict__ Tbf, ushort* __restrict__ Mbf)
{
    int idx = blockIdx.x * blockDim.x + threadIdx.x;
    if (idx < 3200) {
        int r = idx >> 5, c = idx & 31;
        float acc = 0.f;
        for (int k = 0; k < 32; ++k) acc += emb[r*32 + k] * W_s2n[k*32 + c];
        Tbf[idx] = f2bf(acc * SCALE_T);
        return;
    }
    idx -= 3200;
    if (idx < 3*48*64) {
        int lyr = idx / 3072, rem = idx % 3072;
        int row = rem >> 6, u = rem & 63;
        float val = 0.f;
        if (row < 32) {
            int w = row;
            if (u < 32) {
                float a = 0.f;
                for (int k = 0; k < 32; ++k)
                    a += W1[lyr*1024 + u*32 + k] * Ws[lyr*1024 + k*32 + w];
                val = a * SCALE_M1;
            } else if (u < 48) {
                int uu = u - 32; float a = 0.f;
                for (int k = 0; k < 32; ++k)
                    a += W4[lyr*512 + uu*32 + k] * Ws[lyr*1024 + k*32 + w];
                val = a * SCALE_M2;
            }
        } else {
            int w = row - 32;
            if (u < 32) {
                float a = 0.f;
                for (int k = 0; k < 16; ++k)
                    a += W2[lyr*512 + u*16 + k] * Wv[lyr*256 + k*16 + w];
                val = a * SCALE_M34;
            } else if (u < 48) {
                int uu = u - 32; float a = 0.f;
                for (int k = 0; k < 16; ++k)
                    a += W3[lyr*256 + uu*16 + k] * Wv[lyr*256 + k*16 + w];
                val = a * SCALE_M34;
            }
        }
        Mbf[lyr*3072 + row*64 + u] = f2bf(val);
    }
}

// ---------------------------------------------------------------------------
// Fused GNN + MLP: one wave = one graph; 4 graphs/block; 512 blocks.
// LDS 44.2 KB -> 3 blocks/CU (12 waves). Layer loop is wave-private (no
// barriers). M fragments read from global Mbf (L1-hot, preloaded/layer).
// Stage 1: agg[n][u] = feat x Adj^T (m89 scheme, D col=n, rows=u).
// Stage 2 FLIPPED: mfma(agg_frag, M_frag) -> D col=w, rows=node -> packed
// uint2 residual RMW. Packing via v_cvt_pk_bf16_f32 (1 op per 2 values).
// ---------------------------------------------------------------------------
__global__ __launch_bounds__(256)
void gnn_kernel(const float* __restrict__ pos, const int* __restrict__ z,
                const ushort* __restrict__ Tbf, const ushort* __restrict__ Mbf,
                const float* __restrict__ Wr1, const float* __restrict__ br1,
                const float* __restrict__ Wr2, const float* __restrict__ br2,
                float* __restrict__ out, int B)
{
    __shared__ __align__(16) char smem[45312];
    ushort* featA = (ushort*)smem;                    // 4*80*40*2 = 25600 B
    ushort* aggA  = (ushort*)(smem + 25600);          // 4*32*72*2 = 18432 B
    float*  hgl   = (float*)(smem + 44032);           // 4*80*4    = 1280 B
    float*  h1    = (float*)aggA;                     // alias (post-layers)
    float*  red   = ((float*)aggA) + 1024;            // alias, +4096 B

    const int tid = threadIdx.x;
    const int wv = tid >> 6, l = tid & 63;
    const int g  = blockIdx.x*4 + wv;
    ushort* F  = featA + wv*80*FSTR;
    ushort* AG = aggA  + wv*32*ASTR;

    // zero agg (incl. K-pad cols 48..63) and v feature rows
    for (int i = l; i < 32*(ASTR/2); i += 64) ((uint*)AG)[i] = 0;
    for (int i = l; i < 48*(FSTR/2); i += 64) ((uint*)(F + 32*FSTR))[i] = 0;

    // s init: F[c][n] = Tbf[z[n]][c]  (transposed scatter)
    {
        int n = l & 31, h = l >> 5;
        int zg = z[g*32 + n];
        uint4 t0 = *(const uint4*)(Tbf + zg*32 + h*16);
        uint4 t1 = *(const uint4*)(Tbf + zg*32 + h*16 + 8);
        unsigned ua[8] = {t0.x, t0.y, t0.z, t0.w, t1.x, t1.y, t1.z, t1.w};
        #pragma unroll
        for (int q = 0; q < 8; ++q) {
            F[(h*16 + 2*q    )*FSTR + n] = (ushort)ua[q];
            F[(h*16 + 2*q + 1)*FSTR + n] = (ushort)(ua[q] >> 16);
        }
    }

    // adjacency fragments inline (layer-invariant, 32 VGPRs)
    const int ln = l & 15, kq = l >> 4;
    bf16x8 adjf[4][2];
    {
        const int k0 = kq*8;
        #pragma unroll
        for (int nt = 0; nt < 2; ++nt) {
            int ng = g*32 + nt*16 + ln;
            float px = pos[3*ng], py = pos[3*ng+1], pz = pos[3*ng+2];
            union { bf16x8 v; ushort s[8]; } o[4];
            #pragma unroll
            for (int jj = 0; jj < 8; ++jj) {
                int j = g*32 + k0 + jj;
                float dx = __fsub_rn(px, pos[3*j]);
                float dy = __fsub_rn(py, pos[3*j+1]);
                float dz = __fsub_rn(pz, pos[3*j+2]);
                float d2 = __fadd_rn(__fadd_rn(__fmul_rn(dx,dx), __fmul_rn(dy,dy)),
                                     __fmul_rn(dz,dz));
                bool on = (d2 <= 25.0f) && (d2 > 0.0f);
                float rinv = on ? rsqrtf(d2) * SQRT3F : 0.f;
                o[0].s[jj] = on ? (ushort)0x3F80 : (ushort)0;   // bf16(1.0)
                o[1].s[jj] = f2bf(dx * rinv);
                o[2].s[jj] = f2bf(dy * rinv);
                o[3].s[jj] = f2bf(dz * rinv);
            }
            #pragma unroll
            for (int w = 0; w < 4; ++w) adjf[w][nt] = o[w].v;
        }
    }

    const f32x4 z4 = {0.f, 0.f, 0.f, 0.f};

    for (int lay = 0; lay < 3; ++lay) {
        const ushort* Mg = Mbf + lay*3072;
        // feature fragments (pre-update values)
        bf16x8 fs0 = *(const bf16x8*)&F[(     ln)*FSTR + kq*8];
        bf16x8 fs1 = *(const bf16x8*)&F[(16 + ln)*FSTR + kq*8];
        bf16x8 fv0 = *(const bf16x8*)&F[(32 + ln)*FSTR + kq*8];
        bf16x8 fv1 = *(const bf16x8*)&F[(48 + ln)*FSTR + kq*8];
        bf16x8 fv2 = *(const bf16x8*)&F[(64 + ln)*FSTR + kq*8];
        // M fragments for this layer (global, L1-hot)
        bf16x8 bmS0[2], bmS1[2], bmV[2];
        #pragma unroll
        for (int kc = 0; kc < 2; ++kc) {
            bmS0[kc] = *(const bf16x8*)&Mg[(     ln)*64 + kc*32 + kq*8];
            bmS1[kc] = *(const bf16x8*)&Mg[(16 + ln)*64 + kc*32 + kq*8];
            bmV [kc] = *(const bf16x8*)&Mg[(32 + ln)*64 + kc*32 + kq*8];
        }

        // ---- scalar path: agg = [A0 (u<32) | a3 (u 32..47)]
        #pragma unroll
        for (int nt = 0; nt < 2; ++nt) {
            f32x4 t;
            t = mfma(fs0, adjf[0][nt], z4);
            storeAgg(AG, t,      kq*4, nt*16 + ln);
            t = mfma(fs1, adjf[0][nt], z4);
            storeAgg(AG, t, 16 + kq*4, nt*16 + ln);
            t = mfma(fv2, adjf[3][nt], z4);
            t = mfma(fv1, adjf[2][nt], t);
            t = mfma(fv0, adjf[1][nt], t);
            storeAgg(AG, t, 32 + kq*4, nt*16 + ln);
        }
        f32x4 hs[2][2] = {{z4, z4}, {z4, z4}};   // [node-tile][w-tile]
        #pragma unroll
        for (int kc = 0; kc < 2; ++kc)
            #pragma unroll
            for (int mt = 0; mt < 2; ++mt) {
                bf16x8 ag = *(const bf16x8*)&AG[(mt*16 + ln)*ASTR + kc*32 + kq*8];
                hs[mt][0] = mfma(ag, bmS0[kc], hs[mt][0]);
                hs[mt][1] = mfma(ag, bmS1[kc], hs[mt][1]);
            }
        #pragma unroll
        for (int mt = 0; mt < 2; ++mt)
            #pragma unroll
            for (int wt = 0; wt < 2; ++wt)
                rmw4(F, wt*16 + ln, mt*16 + kq*4, hs[mt][wt]);

        // ---- vector path, one spatial component i at a time (reuses AG)
        #pragma unroll
        for (int i = 0; i < 3; ++i) {
            bf16x8 fvi = (i == 0) ? fv0 : (i == 1) ? fv1 : fv2;
            #pragma unroll
            for (int nt = 0; nt < 2; ++nt) {
                f32x4 t;
                t = mfma(fs0, adjf[1+i][nt], z4);
                storeAgg(AG, t,      kq*4, nt*16 + ln);
                t = mfma(fs1, adjf[1+i][nt], z4);
                storeAgg(AG, t, 16 + kq*4, nt*16 + ln);
                t = mfma(fvi, adjf[0][nt], z4);
                storeAgg(AG, t, 32 + kq*4, nt*16 + ln);
            }
            f32x4 hv[2] = {z4, z4};
            #pragma unroll
            for (int kc = 0; kc < 2; ++kc)
                #pragma unroll
                for (int mt = 0; mt < 2; ++mt) {
                    bf16x8 ag = *(const bf16x8*)&AG[(mt*16 + ln)*ASTR + kc*32 + kq*8];
                    hv[mt] = mfma(ag, bmV[kc], hv[mt]);
                }
            #pragma unroll
            for (int mt = 0; mt < 2; ++mt)
                rmw4(F, 32 + i*16 + ln, mt*16 + kq*4, hv[mt]);
        }
    }

    // wave-local sum-pool -> hgl[wv][80]
    for (int f = l; f < 80; f += 64) {
        const ushort* row;
        if (f < 32) row = &F[f*FSTR];
        else { int c = f - 32, w = c/3, i = c - 3*w; row = &F[(32 + i*16 + w)*FSTR]; }
        const uint* r32 = (const uint*)row;
        float acc = 0.f;
        #pragma unroll
        for (int q = 0; q < 16; ++q) {
            uint u = r32[q];
            acc += bf2f((ushort)u) + bf2f((ushort)(u >> 16));
        }
        hgl[wv*80 + f] = acc;
    }
    __syncthreads();   // all waves done with agg; hgl complete

    // --- fused MLP head (block = its 4 graphs) ---
    {
        const int w = tid;
        float acc0 = br1[w];
        float acc1 = acc0, acc2 = acc0, acc3 = acc0;
        #pragma unroll 4
        for (int f = 0; f < 80; ++f) {
            float wvv = Wr1[f*256 + w];
            acc0 = fmaf(hgl[0*80 + f], wvv, acc0);
            acc1 = fmaf(hgl[1*80 + f], wvv, acc1);
            acc2 = fmaf(hgl[2*80 + f], wvv, acc2);
            acc3 = fmaf(hgl[3*80 + f], wvv, acc3);
        }
        h1[0*256 + w] = fmaxf(acc0, 0.f);
        h1[1*256 + w] = fmaxf(acc1, 0.f);
        h1[2*256 + w] = fmaxf(acc2, 0.f);
        h1[3*256 + w] = fmaxf(acc3, 0.f);
    }
    __syncthreads();
    {
        const int g0 = blockIdx.x * 4;
        const int w2 = tid & 127, kh = tid >> 7;
        const float4* h1v = (const float4*)h1;   // [4][64] float4 view
        float s0 = 0.f, s1 = 0.f, s2 = 0.f, s3 = 0.f;
        #pragma unroll 2
        for (int k4 = kh*32; k4 < kh*32 + 32; ++k4) {
            float4 hA = h1v[0*64 + k4];
            float4 hB = h1v[1*64 + k4];
            float4 hC = h1v[2*64 + k4];
            float4 hD = h1v[3*64 + k4];
            int k = k4 * 4;
            float m0 = Wr2[(size_t)(k+0)*128 + w2];
            float m1 = Wr2[(size_t)(k+1)*128 + w2];
            float m2 = Wr2[(size_t)(k+2)*128 + w2];
            float m3 = Wr2[(size_t)(k+3)*128 + w2];
            s0 = fmaf(hA.x,m0, fmaf(hA.y,m1, fmaf(hA.z,m2, fmaf(hA.w,m3, s0))));
            s1 = fmaf(hB.x,m0, fmaf(hB.y,m1, fmaf(hB.z,m2, fmaf(hB.w,m3, s1))));
            s2 = fmaf(hC.x,m0, fmaf(hC.y,m1, fmaf(hC.z,m2, fmaf(hC.w,m3, s2))));
            s3 = fmaf(hD.x,m0, fmaf(hD.y,m1, fmaf(hD.z,m2, fmaf(hD.w,m3, s3))));
        }
        if (kh) {
            red[0*128 + w2] = s0; red[1*128 + w2] = s1;
            red[2*128 + w2] = s2; red[3*128 + w2] = s3;
        }
        __syncthreads();
        if (!kh) {
            float b = br2[w2];
            out[(size_t)(g0+0)*128 + w2] = s0 + red[0*128 + w2] + b;
            out[(size_t)(g0+1)*128 + w2] = s1 + red[1*128 + w2] + b;
            out[(size_t)(g0+2)*128 + w2] = s2 + red[2*128 + w2] + b;
            out[(size_t)(g0+3)*128 + w2] = s3 + red[3*128 + w2] + b;
        }
    }
}

// ---------------------------------------------------------------------------
extern "C" void kernel_launch(void* const* d_in, const int* in_sizes, int n_in,
                              void* d_out, int out_size, void* d_ws, size_t ws_size,
                              hipStream_t stream)
{
    const float* pos   = (const float*)d_in[0];
    const int*   z     = (const int*)d_in[1];
    const float* emb   = (const float*)d_in[5];
    const float* W_s2n = (const float*)d_in[6];
    const float* W1    = (const float*)d_in[7];
    const float* W2    = (const float*)d_in[8];
    const float* W3    = (const float*)d_in[9];
    const float* W4    = (const float*)d_in[10];
    const float* Ws    = (const float*)d_in[11];
    const float* Wv    = (const float*)d_in[12];
    const float* Wr1   = (const float*)d_in[13];
    const float* br1   = (const float*)d_in[14];
    const float* Wr2   = (const float*)d_in[15];
    const float* br2   = (const float*)d_in[16];
    float* out = (float*)d_out;

    const int B = out_size / 128;      // graphs (2048)

    // workspace: Tbf (3200 shorts) | Mbf (9216 shorts)
    char* p = (char*)d_ws;
    ushort* Tbf = (ushort*)p;  p += 6400;
    ushort* Mbf = (ushort*)p;  p += 18432;

    const int prep_total = 3200 + 3*48*64;
    prep_kernel<<<(prep_total + 255) / 256, 256, 0, stream>>>(
        emb, W_s2n, W1, W2, W3, W4, Ws, Wv, Tbf, Mbf);

    gnn_kernel<<<B / 4, 256, 0, stream>>>(pos, z, Tbf, Mbf,
                                          Wr1, br1, Wr2, br2, out, B);
}

// Round 7
// 112.800 us; speedup vs baseline: 1.0745x; 1.0092x over previous
//
#include <hip/hip_runtime.h>
#include <math.h>

typedef __attribute__((ext_vector_type(8))) short bf16x8;   // 8 bf16 (4 VGPRs)
typedef __attribute__((ext_vector_type(4))) float f32x4;    // MFMA acc

#define SQRT3F     1.7320508075688772f
#define SCALE_T    0.17677669529663687f    // 1/sqrt(32)
#define SCALE_M1   0.025515518153991442f   // C_SCALAR/sqrt(32)
#define SCALE_M2   0.014731391274719739f   // C_SCALAR*inv_sqrt3/sqrt(32)
#define SCALE_M34  0.036084391824351615f   // C_SCALAR/4

#define FSTR 40    // feature row stride (shorts): 80 B

__device__ __forceinline__ ushort f2bf(float f) {
    union { float f; unsigned u; } v; v.f = f;
    unsigned u = v.u;
    return (ushort)((u + 0x7FFFu + ((u >> 16) & 1u)) >> 16);
}
__device__ __forceinline__ float bf2f(ushort h) {
    union { unsigned u; float f; } v; v.u = ((unsigned)h) << 16;
    return v.f;
}
// compiler-visible packed bf16 pair (int ops; hazard-safe producer)
__device__ __forceinline__ unsigned packbf(float lo, float hi) {
    return (unsigned)f2bf(lo) | ((unsigned)f2bf(hi) << 16);
}
// asm cvt_pk ONLY where the consumer is a ds_write (proven safe, round 4)
__device__ __forceinline__ unsigned cvtpk(float lo, float hi) {
    unsigned r;
    asm("v_cvt_pk_bf16_f32 %0, %1, %2" : "=v"(r) : "v"(lo), "v"(hi));
    return r;
}
// permlane swaps via BUILTINS (compiler inserts hazard waits; raw asm NaN'd).
// pl32: a'={a.r0,a.r1,b.r0,b.r1}, b'={a.r2,a.r3,b.r2,b.r3}  (16-lane rows)
// pl16: a'={a.r0,b.r0,a.r2,b.r2}, b'={a.r1,b.r1,a.r3,b.r3}
__device__ __forceinline__ void pl32(unsigned &a, unsigned &b) {
    auto r = __builtin_amdgcn_permlane32_swap(a, b, false, false);
    a = r[0]; b = r[1];
}
__device__ __forceinline__ void pl16(unsigned &a, unsigned &b) {
    auto r = __builtin_amdgcn_permlane16_swap(a, b, false, false);
    a = r[0]; b = r[1];
}
__device__ __forceinline__ f32x4 mfma(bf16x8 a, bf16x8 b, f32x4 c) {
    return __builtin_amdgcn_mfma_f32_16x16x32_bf16(a, b, c, 0, 0, 0);
}
// Relayout stage-1 acc tiles (T0=u0..15, T1=u16..31, T2=u32..47) into
// stage-2 A-operand fragments, entirely in registers (no LDS roundtrip).
// f0 = k-block u0..31, f1 = k-block u32..63 (u48..63 zero pad).
// Derivation (ISA-checked): D lane(ln,kq) holds u=kq*4+q col ln; A-frag
// lane(ln,kq) needs u=kq*8+e row ln. word w of f0 = [p0@2kq, p1@2kq,
// p0@(2kq+1), p1@(2kq+1)] which is exactly pl32;pl16 on (p0,q0),(p1,q1).
__device__ __forceinline__ void makeFrags(f32x4 T0, f32x4 T1, f32x4 T2,
                                          bf16x8 &f0, bf16x8 &f1) {
    unsigned p0 = packbf(T0[0], T0[1]), p1 = packbf(T0[2], T0[3]);
    unsigned q0 = packbf(T1[0], T1[1]), q1 = packbf(T1[2], T1[3]);
    unsigned s0 = packbf(T2[0], T2[1]), s1 = packbf(T2[2], T2[3]);
    pl32(p0, q0); pl16(p0, q0);      // p0 -> word0, q0 -> word2
    pl32(p1, q1); pl16(p1, q1);      // p1 -> word1, q1 -> word3
    unsigned z0 = 0u, z1 = 0u;
    pl32(s0, z0); pl16(s0, z0);      // rows 2,3 (k=48..63) get zeros
    pl32(s1, z1); pl16(s1, z1);
    union { bf16x8 v; unsigned u[4]; } r;
    r.u[0] = p0; r.u[1] = p1; r.u[2] = q0; r.u[3] = q1; f0 = r.v;
    r.u[0] = s0; r.u[1] = s1; r.u[2] = z0; r.u[3] = z1; f1 = r.v;
}
// residual + relu RMW of 4 consecutive nodes at channel c (packed uint2)
__device__ __forceinline__ void rmw4(ushort* F, int c, int n0, f32x4 h) {
    uint2* p = (uint2*)&F[c*FSTR + n0];
    uint2 o = *p;
    float f0 = bf2f((ushort)(o.x      )) + fmaxf(h[0], 0.f);
    float f1 = bf2f((ushort)(o.x >> 16)) + fmaxf(h[1], 0.f);
    float f2 = bf2f((ushort)(o.y      )) + fmaxf(h[2], 0.f);
    float f3 = bf2f((ushort)(o.y >> 16)) + fmaxf(h[3], 0.f);
    uint2 w;
    w.x = cvtpk(f0, f1);
    w.y = cvtpk(f2, f3);
    *p = w;
}

// ---------------------------------------------------------------------------
// Prep (tiny, one-shot): Tbf = bf16(emb@W_s2n * sT)  (100x32)
//   Mbf[lyr][row][64]: rows 0..31 = MsT[w][u], rows 32..47 = MvT[w][u],
//   cols 48..63 zero (K-pad). Executed ONCE — in-kernel block-redundant
//   folds regress (round-3: +8us from lost occupancy + cold-latency fold).
// ---------------------------------------------------------------------------
__global__ void prep_kernel(const float* __restrict__ emb,
                            const float* __restrict__ W_s2n,
                            const float* __restrict__ W1, const float* __restrict__ W2,
                            const float* __restrict__ W3, const float* __restrict__ W4,
                            const float* __restrict__ Ws, const float* __restrict__ Wv,
                            ushort* __restrict__ Tbf, ushort* __restrict__ Mbf)
{
    int idx = blockIdx.x * blockDim.x + threadIdx.x;
    if (idx < 3200) {
        int r = idx >> 5, c = idx & 31;
        float acc = 0.f;
        for (int k = 0; k < 32; ++k) acc += emb[r*32 + k] * W_s2n[k*32 + c];
        Tbf[idx] = f2bf(acc * SCALE_T);
        return;
    }
    idx -= 3200;
    if (idx < 3*48*64) {
        int lyr = idx / 3072, rem = idx % 3072;
        int row = rem >> 6, u = rem & 63;
        float val = 0.f;
        if (row < 32) {
            int w = row;
            if (u < 32) {
                float a = 0.f;
                for (int k = 0; k < 32; ++k)
                    a += W1[lyr*1024 + u*32 + k] * Ws[lyr*1024 + k*32 + w];
                val = a * SCALE_M1;
            } else if (u < 48) {
                int uu = u - 32; float a = 0.f;
                for (int k = 0; k < 32; ++k)
                    a += W4[lyr*512 + uu*32 + k] * Ws[lyr*1024 + k*32 + w];
                val = a * SCALE_M2;
            }
        } else {
            int w = row - 32;
            if (u < 32) {
                float a = 0.f;
                for (int k = 0; k < 16; ++k)
                    a += W2[lyr*512 + u*16 + k] * Wv[lyr*256 + k*16 + w];
                val = a * SCALE_M34;
            } else if (u < 48) {
                int uu = u - 32; float a = 0.f;
                for (int k = 0; k < 16; ++k)
                    a += W3[lyr*256 + uu*16 + k] * Wv[lyr*256 + k*16 + w];
                val = a * SCALE_M34;
            }
        }
        Mbf[lyr*3072 + row*64 + u] = f2bf(val);
    }
}

// ---------------------------------------------------------------------------
// Fused GNN + MLP: one wave = one graph; 4 graphs/block; 512 blocks.
// Stage-1 -> stage-2 handoff fully in-register: acc tiles repacked into
// A-operand fragments via packbf + permlane32/16_swap builtins (no agg LDS
// buffer, no lgkmcnt on the dep chain, 12 independent sections/layer).
// LDS 26.9 KB -> 5 blocks/CU (20 waves, was 12).
// ---------------------------------------------------------------------------
__global__ __launch_bounds__(256)
void gnn_kernel(const float* __restrict__ pos, const int* __restrict__ z,
                const ushort* __restrict__ Tbf, const ushort* __restrict__ Mbf,
                const float* __restrict__ Wr1, const float* __restrict__ br1,
                const float* __restrict__ Wr2, const float* __restrict__ br2,
                float* __restrict__ out, int B)
{
    __shared__ __align__(16) char smem[26880];
    ushort* featA = (ushort*)smem;                    // 4*80*40*2 = 25600 B
    float*  hgl   = (float*)(smem + 25600);           // 4*80*4    = 1280 B
    float*  h1    = (float*)smem;                     // alias featA (post-layers)
    float*  red   = (float*)(smem + 4096);            // alias featA, after h1

    const int tid = threadIdx.x;
    const int wv = tid >> 6, l = tid & 63;
    const int g  = blockIdx.x*4 + wv;
    ushort* F  = featA + wv*80*FSTR;

    // zero v feature rows
    for (int i = l; i < 48*(FSTR/2); i += 64) ((uint*)(F + 32*FSTR))[i] = 0;

    // s init: F[c][n] = Tbf[z[n]][c]  (transposed scatter)
    {
        int n = l & 31, h = l >> 5;
        int zg = z[g*32 + n];
        uint4 t0 = *(const uint4*)(Tbf + zg*32 + h*16);
        uint4 t1 = *(const uint4*)(Tbf + zg*32 + h*16 + 8);
        unsigned ua[8] = {t0.x, t0.y, t0.z, t0.w, t1.x, t1.y, t1.z, t1.w};
        #pragma unroll
        for (int q = 0; q < 8; ++q) {
            F[(h*16 + 2*q    )*FSTR + n] = (ushort)ua[q];
            F[(h*16 + 2*q + 1)*FSTR + n] = (ushort)(ua[q] >> 16);
        }
    }

    // adjacency fragments inline (layer-invariant, 32 VGPRs)
    const int ln = l & 15, kq = l >> 4;
    bf16x8 adjf[4][2];
    {
        const int k0 = kq*8;
        #pragma unroll
        for (int nt = 0; nt < 2; ++nt) {
            int ng = g*32 + nt*16 + ln;
            float px = pos[3*ng], py = pos[3*ng+1], pz = pos[3*ng+2];
            union { bf16x8 v; ushort s[8]; } o[4];
            #pragma unroll
            for (int jj = 0; jj < 8; ++jj) {
                int j = g*32 + k0 + jj;
                float dx = __fsub_rn(px, pos[3*j]);
                float dy = __fsub_rn(py, pos[3*j+1]);
                float dz = __fsub_rn(pz, pos[3*j+2]);
                float d2 = __fadd_rn(__fadd_rn(__fmul_rn(dx,dx), __fmul_rn(dy,dy)),
                                     __fmul_rn(dz,dz));
                bool on = (d2 <= 25.0f) && (d2 > 0.0f);
                float rinv = on ? rsqrtf(d2) * SQRT3F : 0.f;
                o[0].s[jj] = on ? (ushort)0x3F80 : (ushort)0;   // bf16(1.0)
                o[1].s[jj] = f2bf(dx * rinv);
                o[2].s[jj] = f2bf(dy * rinv);
                o[3].s[jj] = f2bf(dz * rinv);
            }
            #pragma unroll
            for (int w = 0; w < 4; ++w) adjf[w][nt] = o[w].v;
        }
    }

    const f32x4 z4 = {0.f, 0.f, 0.f, 0.f};

    for (int lay = 0; lay < 3; ++lay) {
        const ushort* Mg = Mbf + lay*3072;
        // feature fragments (pre-update values)
        bf16x8 fs0 = *(const bf16x8*)&F[(     ln)*FSTR + kq*8];
        bf16x8 fs1 = *(const bf16x8*)&F[(16 + ln)*FSTR + kq*8];
        bf16x8 fv0 = *(const bf16x8*)&F[(32 + ln)*FSTR + kq*8];
        bf16x8 fv1 = *(const bf16x8*)&F[(48 + ln)*FSTR + kq*8];
        bf16x8 fv2 = *(const bf16x8*)&F[(64 + ln)*FSTR + kq*8];
        // M fragments for this layer (global, L1-hot)
        bf16x8 bmS0[2], bmS1[2], bmV[2];
        #pragma unroll
        for (int kc = 0; kc < 2; ++kc) {
            bmS0[kc] = *(const bf16x8*)&Mg[(     ln)*64 + kc*32 + kq*8];
            bmS1[kc] = *(const bf16x8*)&Mg[(16 + ln)*64 + kc*32 + kq*8];
            bmV [kc] = *(const bf16x8*)&Mg[(32 + ln)*64 + kc*32 + kq*8];
        }

        bf16x8 agf[2][2];   // [node-tile][k-block] stage-2 A fragments

        // ---- scalar path: agg rows = [A0*s (u<32) | sum_i Ai*v_i (u32..47)]
        #pragma unroll
        for (int nt = 0; nt < 2; ++nt) {
            f32x4 T0 = mfma(fs0, adjf[0][nt], z4);
            f32x4 T1 = mfma(fs1, adjf[0][nt], z4);
            f32x4 T2 = mfma(fv2, adjf[3][nt], z4);
            T2 = mfma(fv1, adjf[2][nt], T2);
            T2 = mfma(fv0, adjf[1][nt], T2);
            makeFrags(T0, T1, T2, agf[nt][0], agf[nt][1]);
        }
        f32x4 hs[2][2] = {{z4, z4}, {z4, z4}};   // [node-tile][w-tile]
        #pragma unroll
        for (int kc = 0; kc < 2; ++kc)
            #pragma unroll
            for (int mt = 0; mt < 2; ++mt) {
                hs[mt][0] = mfma(agf[mt][kc], bmS0[kc], hs[mt][0]);
                hs[mt][1] = mfma(agf[mt][kc], bmS1[kc], hs[mt][1]);
            }
        #pragma unroll
        for (int mt = 0; mt < 2; ++mt)
            #pragma unroll
            for (int wt = 0; wt < 2; ++wt)
                rmw4(F, wt*16 + ln, mt*16 + kq*4, hs[mt][wt]);

        // ---- vector path, one spatial component i at a time
        #pragma unroll
        for (int i = 0; i < 3; ++i) {
            bf16x8 fvi = (i == 0) ? fv0 : (i == 1) ? fv1 : fv2;
            #pragma unroll
            for (int nt = 0; nt < 2; ++nt) {
                f32x4 T0 = mfma(fs0, adjf[1+i][nt], z4);
                f32x4 T1 = mfma(fs1, adjf[1+i][nt], z4);
                f32x4 T2 = mfma(fvi, adjf[0][nt], z4);
                makeFrags(T0, T1, T2, agf[nt][0], agf[nt][1]);
            }
            f32x4 hv[2] = {z4, z4};
            #pragma unroll
            for (int kc = 0; kc < 2; ++kc)
                #pragma unroll
                for (int mt = 0; mt < 2; ++mt)
                    hv[mt] = mfma(agf[mt][kc], bmV[kc], hv[mt]);
            #pragma unroll
            for (int mt = 0; mt < 2; ++mt)
                rmw4(F, 32 + i*16 + ln, mt*16 + kq*4, hv[mt]);
        }
    }

    // wave-local sum-pool -> hgl[wv][80]
    for (int f = l; f < 80; f += 64) {
        const ushort* row;
        if (f < 32) row = &F[f*FSTR];
        else { int c = f - 32, w = c/3, i = c - 3*w; row = &F[(32 + i*16 + w)*FSTR]; }
        const uint* r32 = (const uint*)row;
        float acc = 0.f;
        #pragma unroll
        for (int q = 0; q < 16; ++q) {
            uint u = r32[q];
            acc += bf2f((ushort)u) + bf2f((ushort)(u >> 16));
        }
        hgl[wv*80 + f] = acc;
    }
    __syncthreads();   // hgl complete; featA (F) dead -> h1/red alias safe

    // --- fused MLP head (block = its 4 graphs) ---
    {
        const int w = tid;
        float acc0 = br1[w];
        float acc1 = acc0, acc2 = acc0, acc3 = acc0;
        #pragma unroll 4
        for (int f = 0; f < 80; ++f) {
            float wvv = Wr1[f*256 + w];
            acc0 = fmaf(hgl[0*80 + f], wvv, acc0);
            acc1 = fmaf(hgl[1*80 + f], wvv, acc1);
            acc2 = fmaf(hgl[2*80 + f], wvv, acc2);
            acc3 = fmaf(hgl[3*80 + f], wvv, acc3);
        }
        h1[0*256 + w] = fmaxf(acc0, 0.f);
        h1[1*256 + w] = fmaxf(acc1, 0.f);
        h1[2*256 + w] = fmaxf(acc2, 0.f);
        h1[3*256 + w] = fmaxf(acc3, 0.f);
    }
    __syncthreads();
    {
        const int g0 = blockIdx.x * 4;
        const int w2 = tid & 127, kh = tid >> 7;
        const float4* h1v = (const float4*)h1;   // [4][64] float4 view
        float s0 = 0.f, s1 = 0.f, s2 = 0.f, s3 = 0.f;
        #pragma unroll 2
        for (int k4 = kh*32; k4 < kh*32 + 32; ++k4) {
            float4 hA = h1v[0*64 + k4];
            float4 hB = h1v[1*64 + k4];
            float4 hC = h1v[2*64 + k4];
            float4 hD = h1v[3*64 + k4];
            int k = k4 * 4;
            float m0 = Wr2[(size_t)(k+0)*128 + w2];
            float m1 = Wr2[(size_t)(k+1)*128 + w2];
            float m2 = Wr2[(size_t)(k+2)*128 + w2];
            float m3 = Wr2[(size_t)(k+3)*128 + w2];
            s0 = fmaf(hA.x,m0, fmaf(hA.y,m1, fmaf(hA.z,m2, fmaf(hA.w,m3, s0))));
            s1 = fmaf(hB.x,m0, fmaf(hB.y,m1, fmaf(hB.z,m2, fmaf(hB.w,m3, s1))));
            s2 = fmaf(hC.x,m0, fmaf(hC.y,m1, fmaf(hC.z,m2, fmaf(hC.w,m3, s2))));
            s3 = fmaf(hD.x,m0, fmaf(hD.y,m1, fmaf(hD.z,m2, fmaf(hD.w,m3, s3))));
        }
        if (kh) {
            red[0*128 + w2] = s0; red[1*128 + w2] = s1;
            red[2*128 + w2] = s2; red[3*128 + w2] = s3;
        }
        __syncthreads();
        if (!kh) {
            float b = br2[w2];
            out[(size_t)(g0+0)*128 + w2] = s0 + red[0*128 + w2] + b;
            out[(size_t)(g0+1)*128 + w2] = s1 + red[1*128 + w2] + b;
            out[(size_t)(g0+2)*128 + w2] = s2 + red[2*128 + w2] + b;
            out[(size_t)(g0+3)*128 + w2] = s3 + red[3*128 + w2] + b;
        }
    }
}

// ---------------------------------------------------------------------------
extern "C" void kernel_launch(void* const* d_in, const int* in_sizes, int n_in,
                              void* d_out, int out_size, void* d_ws, size_t ws_size,
                              hipStream_t stream)
{
    const float* pos   = (const float*)d_in[0];
    const int*   z     = (const int*)d_in[1];
    const float* emb   = (const float*)d_in[5];
    const float* W_s2n = (const float*)d_in[6];
    const float* W1    = (const float*)d_in[7];
    const float* W2    = (const float*)d_in[8];
    const float* W3    = (const float*)d_in[9];
    const float* W4    = (const float*)d_in[10];
    const float* Ws    = (const float*)d_in[11];
    const float* Wv    = (const float*)d_in[12];
    const float* Wr1   = (const float*)d_in[13];
    const float* br1   = (const float*)d_in[14];
    const float* Wr2   = (const float*)d_in[15];
    const float* br2   = (const float*)d_in[16];
    float* out = (float*)d_out;

    const int B = out_size / 128;      // graphs (2048)

    // workspace: Tbf (3200 shorts) | Mbf (9216 shorts)
    char* p = (char*)d_ws;
    ushort* Tbf = (ushort*)p;  p += 6400;
    ushort* Mbf = (ushort*)p;  p += 18432;

    const int prep_total = 3200 + 3*48*64;
    prep_kernel<<<(prep_total + 255) / 256, 256, 0, stream>>>(
        emb, W_s2n, W1, W2, W3, W4, Ws, Wv, Tbf, Mbf);

    gnn_kernel<<<B / 4, 256, 0, stream>>>(pos, z, Tbf, Mbf,
                                          Wr1, br1, Wr2, br2, out, B);
}

// Round 9
// 110.346 us; speedup vs baseline: 1.0984x; 1.0222x over previous
//
#include <hip/hip_runtime.h>
#include <math.h>

typedef __attribute__((ext_vector_type(8))) short bf16x8;   // 8 bf16 (4 VGPRs)
typedef __attribute__((ext_vector_type(4))) float f32x4;    // MFMA acc

#define SQRT3F     1.7320508075688772f
#define SCALE_T    0.17677669529663687f    // 1/sqrt(32)
#define SCALE_M1   0.025515518153991442f   // C_SCALAR/sqrt(32)
#define SCALE_M2   0.014731391274719739f   // C_SCALAR*inv_sqrt3/sqrt(32)
#define SCALE_M34  0.036084391824351615f   // C_SCALAR/4

#define FSTR 40    // feature row stride (shorts): 80 B

__device__ __forceinline__ ushort f2bf(float f) {
    union { float f; unsigned u; } v; v.f = f;
    unsigned u = v.u;
    return (ushort)((u + 0x7FFFu + ((u >> 16) & 1u)) >> 16);
}
__device__ __forceinline__ float bf2f(ushort h) {
    union { unsigned u; float f; } v; v.u = ((unsigned)h) << 16;
    return v.f;
}
// packed f32->bf16 (RNE) single instruction. Producer is inline asm but the
// def is compiler-visible; permlane consumers are BUILTINS (hazard-handled).
__device__ __forceinline__ unsigned cvtpk(float lo, float hi) {
    unsigned r;
    asm("v_cvt_pk_bf16_f32 %0, %1, %2" : "=v"(r) : "v"(lo), "v"(hi));
    return r;
}
// permlane swaps via BUILTINS (r6 raw-asm version NaN'd: missing hazard nops)
__device__ __forceinline__ void pl32(unsigned &a, unsigned &b) {
    auto r = __builtin_amdgcn_permlane32_swap(a, b, false, false);
    a = r[0]; b = r[1];
}
__device__ __forceinline__ void pl16(unsigned &a, unsigned &b) {
    auto r = __builtin_amdgcn_permlane16_swap(a, b, false, false);
    a = r[0]; b = r[1];
}
__device__ __forceinline__ f32x4 mfma(bf16x8 a, bf16x8 b, f32x4 c) {
    return __builtin_amdgcn_mfma_f32_16x16x32_bf16(a, b, c, 0, 0, 0);
}
// D-layout pair (T0 = reg-rows 0..15, T1 = rows 16..31 of the reg axis) ->
// one A-operand fragment with k = that axis (verified r7). Lane axis fixed.
__device__ __forceinline__ bf16x8 makeFrag(f32x4 T0, f32x4 T1) {
    unsigned p0 = cvtpk(T0[0], T0[1]), p1 = cvtpk(T0[2], T0[3]);
    unsigned q0 = cvtpk(T1[0], T1[1]), q1 = cvtpk(T1[2], T1[3]);
    pl32(p0, q0); pl16(p0, q0);      // p0 -> word0, q0 -> word2
    pl32(p1, q1); pl16(p1, q1);      // p1 -> word1, q1 -> word3
    union { bf16x8 v; unsigned u[4]; } r;
    r.u[0] = p0; r.u[1] = p1; r.u[2] = q0; r.u[3] = q1;
    return r.v;
}
// same, upper 16 k-rows zero (K-pad for the u=32..47 agg block)
__device__ __forceinline__ bf16x8 makeFragZ(f32x4 T2) {
    unsigned s0 = cvtpk(T2[0], T2[1]), s1 = cvtpk(T2[2], T2[3]);
    unsigned z0 = 0u, z1 = 0u;
    pl32(s0, z0); pl16(s0, z0);
    pl32(s1, z1); pl16(s1, z1);
    union { bf16x8 v; unsigned u[4]; } r;
    r.u[0] = s0; r.u[1] = s1; r.u[2] = z0; r.u[3] = z1;
    return r.v;
}
// residual + relu, f32 register state
__device__ __forceinline__ void accRelu(f32x4 &S, f32x4 h) {
    S[0] += fmaxf(h[0], 0.f); S[1] += fmaxf(h[1], 0.f);
    S[2] += fmaxf(h[2], 0.f); S[3] += fmaxf(h[3], 0.f);
}

// ---------------------------------------------------------------------------
// Prep (tiny, one-shot): Tbf = bf16(emb@W_s2n * sT)  (100x32)
//   Mbf[lyr][row][64]: rows 0..31 = MsT[w][u], rows 32..47 = MvT[w][u],
//   cols 48..63 zero (K-pad). Executed ONCE — in-kernel block-redundant
//   folds regress (round-3: +8us from lost occupancy + cold-latency fold).
// ---------------------------------------------------------------------------
__global__ void prep_kernel(const float* __restrict__ emb,
                            const float* __restrict__ W_s2n,
                            const float* __restrict__ W1, const float* __restrict__ W2,
                            const float* __restrict__ W3, const float* __restrict__ W4,
                            const float* __restrict__ Ws, const float* __restrict__ Wv,
                            ushort* __restrict__ Tbf, ushort* __restrict__ Mbf)
{
    int idx = blockIdx.x * blockDim.x + threadIdx.x;
    if (idx < 3200) {
        int r = idx >> 5, c = idx & 31;
        float acc = 0.f;
        for (int k = 0; k < 32; ++k) acc += emb[r*32 + k] * W_s2n[k*32 + c];
        Tbf[idx] = f2bf(acc * SCALE_T);
        return;
    }
    idx -= 3200;
    if (idx < 3*48*64) {
        int lyr = idx / 3072, rem = idx % 3072;
        int row = rem >> 6, u = rem & 63;
        float val = 0.f;
        if (row < 32) {
            int w = row;
            if (u < 32) {
                float a = 0.f;
                for (int k = 0; k < 32; ++k)
                    a += W1[lyr*1024 + u*32 + k] * Ws[lyr*1024 + k*32 + w];
                val = a * SCALE_M1;
            } else if (u < 48) {
                int uu = u - 32; float a = 0.f;
                for (int k = 0; k < 32; ++k)
                    a += W4[lyr*512 + uu*32 + k] * Ws[lyr*1024 + k*32 + w];
                val = a * SCALE_M2;
            }
        } else {
            int w = row - 32;
            if (u < 32) {
                float a = 0.f;
                for (int k = 0; k < 16; ++k)
                    a += W2[lyr*512 + u*16 + k] * Wv[lyr*256 + k*16 + w];
                val = a * SCALE_M34;
            } else if (u < 48) {
                int uu = u - 32; float a = 0.f;
                for (int k = 0; k < 16; ++k)
                    a += W3[lyr*256 + uu*16 + k] * Wv[lyr*256 + k*16 + w];
                val = a * SCALE_M34;
            }
        }
        Mbf[lyr*3072 + row*64 + u] = f2bf(val);
    }
}

// ---------------------------------------------------------------------------
// Fused GNN + MLP: one wave = one graph; 4 graphs/block; 512 blocks.
// Feature state lives in f32 REGISTERS across the whole layer loop:
//   Ss[2][2] (32 s-ch x 32 nodes), Sv[2][3] (16 v-ch x 3 x 32 nodes),
//   D-layout (channel in lane, node in regs). Per layer: A-frags derived
//   from state via cvtpk+permlane; residual+relu = register fadd/fmax.
//   ZERO LDS in the layer loop (M loads are L1-hot global). F LDS used
//   only for init scatter and one final write-back feeding the pooling.
// ---------------------------------------------------------------------------
__global__ __launch_bounds__(256)
void gnn_kernel(const float* __restrict__ pos, const int* __restrict__ z,
                const ushort* __restrict__ Tbf, const ushort* __restrict__ Mbf,
                const float* __restrict__ Wr1, const float* __restrict__ br1,
                const float* __restrict__ Wr2, const float* __restrict__ br2,
                float* __restrict__ out, int B)
{
    __shared__ __align__(16) char smem[26880];
    ushort* featA = (ushort*)smem;                    // 4*80*40*2 = 25600 B
    float*  hgl   = (float*)(smem + 25600);           // 4*80*4    = 1280 B
    float*  h1    = (float*)smem;                     // alias featA (post-layers)
    float*  red   = (float*)(smem + 4096);            // alias featA, after h1

    const int tid = threadIdx.x;
    const int wv = tid >> 6, l = tid & 63;
    const int g  = blockIdx.x*4 + wv;
    ushort* F  = featA + wv*80*FSTR;
    const int ln = l & 15, kq = l >> 4;

    // s init: F[c][n] = Tbf[z[n]][c]  (transposed scatter, wave-private)
    {
        int n = l & 31, h = l >> 5;
        int zg = z[g*32 + n];
        uint4 t0 = *(const uint4*)(Tbf + zg*32 + h*16);
        uint4 t1 = *(const uint4*)(Tbf + zg*32 + h*16 + 8);
        unsigned ua[8] = {t0.x, t0.y, t0.z, t0.w, t1.x, t1.y, t1.z, t1.w};
        #pragma unroll
        for (int q = 0; q < 8; ++q) {
            F[(h*16 + 2*q    )*FSTR + n] = (ushort)ua[q];
            F[(h*16 + 2*q + 1)*FSTR + n] = (ushort)(ua[q] >> 16);
        }
    }

    // register feature state, D-layout: lane=channel, regs=node (mt*16+kq*4+q)
    f32x4 Ss[2][2];            // [node-tile][s-ch-tile]
    f32x4 Sv[2][3];            // [node-tile][spatial i], v-ch = lane
    #pragma unroll
    for (int mt = 0; mt < 2; ++mt) {
        #pragma unroll
        for (int wt = 0; wt < 2; ++wt) {
            uint2 d = *(const uint2*)&F[(wt*16 + ln)*FSTR + mt*16 + kq*4];
            Ss[mt][wt][0] = bf2f((ushort)(d.x      ));
            Ss[mt][wt][1] = bf2f((ushort)(d.x >> 16));
            Ss[mt][wt][2] = bf2f((ushort)(d.y      ));
            Ss[mt][wt][3] = bf2f((ushort)(d.y >> 16));
        }
        #pragma unroll
        for (int i = 0; i < 3; ++i)
            Sv[mt][i] = (f32x4){0.f, 0.f, 0.f, 0.f};
    }

    // adjacency fragments inline (layer-invariant, 32 VGPRs)
    bf16x8 adjf[4][2];
    {
        const int k0 = kq*8;
        #pragma unroll
        for (int nt = 0; nt < 2; ++nt) {
            int ng = g*32 + nt*16 + ln;
            float px = pos[3*ng], py = pos[3*ng+1], pz = pos[3*ng+2];
            union { bf16x8 v; ushort s[8]; } o[4];
            #pragma unroll
            for (int jj = 0; jj < 8; ++jj) {
                int j = g*32 + k0 + jj;
                float dx = __fsub_rn(px, pos[3*j]);
                float dy = __fsub_rn(py, pos[3*j+1]);
                float dz = __fsub_rn(pz, pos[3*j+2]);
                float d2 = __fadd_rn(__fadd_rn(__fmul_rn(dx,dx), __fmul_rn(dy,dy)),
                                     __fmul_rn(dz,dz));
                bool on = (d2 <= 25.0f) && (d2 > 0.0f);
                float rinv = on ? rsqrtf(d2) * SQRT3F : 0.f;
                o[0].s[jj] = on ? (ushort)0x3F80 : (ushort)0;   // bf16(1.0)
                o[1].s[jj] = f2bf(dx * rinv);
                o[2].s[jj] = f2bf(dy * rinv);
                o[3].s[jj] = f2bf(dz * rinv);
            }
            #pragma unroll
            for (int w = 0; w < 4; ++w) adjf[w][nt] = o[w].v;
        }
    }

    const f32x4 z4 = {0.f, 0.f, 0.f, 0.f};

    for (int lay = 0; lay < 3; ++lay) {
        const ushort* Mg = Mbf + lay*3072;
        // A-frags from register state (pre-update values)
        bf16x8 fs0 = makeFrag(Ss[0][0], Ss[1][0]);
        bf16x8 fs1 = makeFrag(Ss[0][1], Ss[1][1]);
        bf16x8 fv0 = makeFrag(Sv[0][0], Sv[1][0]);
        bf16x8 fv1 = makeFrag(Sv[0][1], Sv[1][1]);
        bf16x8 fv2 = makeFrag(Sv[0][2], Sv[1][2]);
        // M fragments for this layer (global, L1-hot)
        bf16x8 bmS0[2], bmS1[2], bmV[2];
        #pragma unroll
        for (int kc = 0; kc < 2; ++kc) {
            bmS0[kc] = *(const bf16x8*)&Mg[(     ln)*64 + kc*32 + kq*8];
            bmS1[kc] = *(const bf16x8*)&Mg[(16 + ln)*64 + kc*32 + kq*8];
            bmV [kc] = *(const bf16x8*)&Mg[(32 + ln)*64 + kc*32 + kq*8];
        }

        bf16x8 agf[2][2];   // [node-tile][k-block] stage-2 A fragments

        // ---- scalar path: agg rows = [A0*s (u<32) | sum_i Ai*v_i (u32..47)]
        #pragma unroll
        for (int nt = 0; nt < 2; ++nt) {
            f32x4 T0 = mfma(fs0, adjf[0][nt], z4);
            f32x4 T1 = mfma(fs1, adjf[0][nt], z4);
            f32x4 T2 = mfma(fv2, adjf[3][nt], z4);
            T2 = mfma(fv1, adjf[2][nt], T2);
            T2 = mfma(fv0, adjf[1][nt], T2);
            agf[nt][0] = makeFrag(T0, T1);
            agf[nt][1] = makeFragZ(T2);
        }
        f32x4 hs[2][2] = {{z4, z4}, {z4, z4}};   // [node-tile][w-tile]
        #pragma unroll
        for (int kc = 0; kc < 2; ++kc)
            #pragma unroll
            for (int mt = 0; mt < 2; ++mt) {
                hs[mt][0] = mfma(agf[mt][kc], bmS0[kc], hs[mt][0]);
                hs[mt][1] = mfma(agf[mt][kc], bmS1[kc], hs[mt][1]);
            }
        #pragma unroll
        for (int mt = 0; mt < 2; ++mt)
            #pragma unroll
            for (int wt = 0; wt < 2; ++wt)
                accRelu(Ss[mt][wt], hs[mt][wt]);

        // ---- vector path, one spatial component i at a time
        #pragma unroll
        for (int i = 0; i < 3; ++i) {
            bf16x8 fvi = (i == 0) ? fv0 : (i == 1) ? fv1 : fv2;
            #pragma unroll
            for (int nt = 0; nt < 2; ++nt) {
                f32x4 T0 = mfma(fs0, adjf[1+i][nt], z4);
                f32x4 T1 = mfma(fs1, adjf[1+i][nt], z4);
                f32x4 T2 = mfma(fvi, adjf[0][nt], z4);
                agf[nt][0] = makeFrag(T0, T1);
                agf[nt][1] = makeFragZ(T2);
            }
            f32x4 hv[2] = {z4, z4};
            #pragma unroll
            for (int kc = 0; kc < 2; ++kc)
                #pragma unroll
                for (int mt = 0; mt < 2; ++mt)
                    hv[mt] = mfma(agf[mt][kc], bmV[kc], hv[mt]);
            #pragma unroll
            for (int mt = 0; mt < 2; ++mt)
                accRelu(Sv[mt][i], hv[mt]);
        }
    }

    // write state back to F (bf16) for the pooling pass
    #pragma unroll
    for (int mt = 0; mt < 2; ++mt) {
        #pragma unroll
        for (int wt = 0; wt < 2; ++wt) {
            uint2 w;
            w.x = cvtpk(Ss[mt][wt][0], Ss[mt][wt][1]);
            w.y = cvtpk(Ss[mt][wt][2], Ss[mt][wt][3]);
            *(uint2*)&F[(wt*16 + ln)*FSTR + mt*16 + kq*4] = w;
        }
        #pragma unroll
        for (int i = 0; i < 3; ++i) {
            uint2 w;
            w.x = cvtpk(Sv[mt][i][0], Sv[mt][i][1]);
            w.y = cvtpk(Sv[mt][i][2], Sv[mt][i][3]);
            *(uint2*)&F[(32 + i*16 + ln)*FSTR + mt*16 + kq*4] = w;
        }
    }

    // wave-local sum-pool -> hgl[wv][80]
    for (int f = l; f < 80; f += 64) {
        const ushort* row;
        if (f < 32) row = &F[f*FSTR];
        else { int c = f - 32, w = c/3, i = c - 3*w; row = &F[(32 + i*16 + w)*FSTR]; }
        const uint* r32 = (const uint*)row;
        float acc = 0.f;
        #pragma unroll
        for (int q = 0; q < 16; ++q) {
            uint u = r32[q];
            acc += bf2f((ushort)u) + bf2f((ushort)(u >> 16));
        }
        hgl[wv*80 + f] = acc;
    }
    __syncthreads();   // hgl complete; featA (F) dead -> h1/red alias safe

    // --- fused MLP head (block = its 4 graphs) ---
    {
        const int w = tid;
        float acc0 = br1[w];
        float acc1 = acc0, acc2 = acc0, acc3 = acc0;
        #pragma unroll 4
        for (int f = 0; f < 80; ++f) {
            float wvv = Wr1[f*256 + w];
            acc0 = fmaf(hgl[0*80 + f], wvv, acc0);
            acc1 = fmaf(hgl[1*80 + f], wvv, acc1);
            acc2 = fmaf(hgl[2*80 + f], wvv, acc2);
            acc3 = fmaf(hgl[3*80 + f], wvv, acc3);
        }
        h1[0*256 + w] = fmaxf(acc0, 0.f);
        h1[1*256 + w] = fmaxf(acc1, 0.f);
        h1[2*256 + w] = fmaxf(acc2, 0.f);
        h1[3*256 + w] = fmaxf(acc3, 0.f);
    }
    __syncthreads();
    {
        const int g0 = blockIdx.x * 4;
        const int w2 = tid & 127, kh = tid >> 7;
        const float4* h1v = (const float4*)h1;   // [4][64] float4 view
        float s0 = 0.f, s1 = 0.f, s2 = 0.f, s3 = 0.f;
        #pragma unroll 2
        for (int k4 = kh*32; k4 < kh*32 + 32; ++k4) {
            float4 hA = h1v[0*64 + k4];
            float4 hB = h1v[1*64 + k4];
            float4 hC = h1v[2*64 + k4];
            float4 hD = h1v[3*64 + k4];
            int k = k4 * 4;
            float m0 = Wr2[(size_t)(k+0)*128 + w2];
            float m1 = Wr2[(size_t)(k+1)*128 + w2];
            float m2 = Wr2[(size_t)(k+2)*128 + w2];
            float m3 = Wr2[(size_t)(k+3)*128 + w2];
            s0 = fmaf(hA.x,m0, fmaf(hA.y,m1, fmaf(hA.z,m2, fmaf(hA.w,m3, s0))));
            s1 = fmaf(hB.x,m0, fmaf(hB.y,m1, fmaf(hB.z,m2, fmaf(hB.w,m3, s1))));
            s2 = fmaf(hC.x,m0, fmaf(hC.y,m1, fmaf(hC.z,m2, fmaf(hC.w,m3, s2))));
            s3 = fmaf(hD.x,m0, fmaf(hD.y,m1, fmaf(hD.z,m2, fmaf(hD.w,m3, s3))));
        }
        if (kh) {
            red[0*128 + w2] = s0; red[1*128 + w2] = s1;
            red[2*128 + w2] = s2; red[3*128 + w2] = s3;
        }
        __syncthreads();
        if (!kh) {
            float b = br2[w2];
            out[(size_t)(g0+0)*128 + w2] = s0 + red[0*128 + w2] + b;
            out[(size_t)(g0+1)*128 + w2] = s1 + red[1*128 + w2] + b;
            out[(size_t)(g0+2)*128 + w2] = s2 + red[2*128 + w2] + b;
            out[(size_t)(g0+3)*128 + w2] = s3 + red[3*128 + w2] + b;
        }
    }
}

// ---------------------------------------------------------------------------
extern "C" void kernel_launch(void* const* d_in, const int* in_sizes, int n_in,
                              void* d_out, int out_size, void* d_ws, size_t ws_size,
                              hipStream_t stream)
{
    const float* pos   = (const float*)d_in[0];
    const int*   z     = (const int*)d_in[1];
    const float* emb   = (const float*)d_in[5];
    const float* W_s2n = (const float*)d_in[6];
    const float* W1    = (const float*)d_in[7];
    const float* W2    = (const float*)d_in[8];
    const float* W3    = (const float*)d_in[9];
    const float* W4    = (const float*)d_in[10];
    const float* Ws    = (const float*)d_in[11];
    const float* Wv    = (const float*)d_in[12];
    const float* Wr1   = (const float*)d_in[13];
    const float* br1   = (const float*)d_in[14];
    const float* Wr2   = (const float*)d_in[15];
    const float* br2   = (const float*)d_in[16];
    float* out = (float*)d_out;

    const int B = out_size / 128;      // graphs (2048)

    // workspace: Tbf (3200 shorts) | Mbf (9216 shorts)
    char* p = (char*)d_ws;
    ushort* Tbf = (ushort*)p;  p += 6400;
    ushort* Mbf = (ushort*)p;  p += 18432;

    const int prep_total = 3200 + 3*48*64;
    prep_kernel<<<(prep_total + 255) / 256, 256, 0, stream>>>(
        emb, W_s2n, W1, W2, W3, W4, Ws, Wv, Tbf, Mbf);

    gnn_kernel<<<B / 4, 256, 0, stream>>>(pos, z, Tbf, Mbf,
                                          Wr1, br1, Wr2, br2, out, B);
}

// Round 12
// 109.190 us; speedup vs baseline: 1.1100x; 1.0106x over previous
//
#include <hip/hip_runtime.h>
#include <math.h>

typedef __attribute__((ext_vector_type(8))) short bf16x8;   // 8 bf16 (4 VGPRs)
typedef __attribute__((ext_vector_type(4))) float f32x4;    // MFMA acc

#define SQRT3F     1.7320508075688772f
#define SCALE_T    0.17677669529663687f    // 1/sqrt(32)
#define SCALE_M1   0.025515518153991442f   // C_SCALAR/sqrt(32)
#define SCALE_M2   0.014731391274719739f   // C_SCALAR*inv_sqrt3/sqrt(32)
#define SCALE_M34  0.036084391824351615f   // C_SCALAR/4

#define FSTR 40    // feature row stride (shorts): 80 B

__device__ __forceinline__ ushort f2bf(float f) {
    union { float f; unsigned u; } v; v.f = f;
    unsigned u = v.u;
    return (ushort)((u + 0x7FFFu + ((u >> 16) & 1u)) >> 16);
}
__device__ __forceinline__ float bf2f(ushort h) {
    union { unsigned u; float f; } v; v.u = ((unsigned)h) << 16;
    return v.f;
}
// packed f32->bf16 (RNE). Safe ONLY when the consumer is ds_write/global
// (r4-proven). NOT safe feeding MFMA directly (r10 NaN: INLINEASM def is
// opaque to the hazard recognizer -> missing VALU-write->MFMA-read waits).
__device__ __forceinline__ unsigned cvtpk(float lo, float hi) {
    unsigned r;
    asm("v_cvt_pk_bf16_f32 %0, %1, %2" : "=v"(r) : "v"(lo), "v"(hi));
    return r;
}
__device__ __forceinline__ f32x4 mfma(bf16x8 a, bf16x8 b, f32x4 c) {
    return __builtin_amdgcn_mfma_f32_16x16x32_bf16(a, b, c, 0, 0, 0);
}
// ---- sigma-permuted A-fragment packs (NO cross-lane ops) ----
// Hardware k slot kq*8+e holds logical index sigma(kq,e)=(e>>2)*16+kq*4+(e&3).
// B-operands (adjacency, M) are stored with the same sigma on their k axis,
// so stage-1/stage-2 A-frags are pure per-lane cvtpk packs of D-tiles.
// HAZARD-HARDENED (r10 post-mortem): one asm block per fragment, early-
// clobber outputs, trailing s_nop 3 = deterministic VALU->MFMA wait states.
__device__ __forceinline__ bf16x8 frag2(f32x4 A, f32x4 B) {
    union { bf16x8 v; unsigned u[4]; } r;
    asm("v_cvt_pk_bf16_f32 %0, %4, %5\n\t"
        "v_cvt_pk_bf16_f32 %1, %6, %7\n\t"
        "v_cvt_pk_bf16_f32 %2, %8, %9\n\t"
        "v_cvt_pk_bf16_f32 %3, %10, %11\n\t"
        "s_nop 3"
        : "=&v"(r.u[0]), "=&v"(r.u[1]), "=&v"(r.u[2]), "=&v"(r.u[3])
        : "v"(A[0]), "v"(A[1]), "v"(A[2]), "v"(A[3]),
          "v"(B[0]), "v"(B[1]), "v"(B[2]), "v"(B[3]));
    return r.v;
}
__device__ __forceinline__ bf16x8 frag1z(f32x4 A) {
    union { bf16x8 v; unsigned u[4]; } r;
    asm("v_cvt_pk_bf16_f32 %0, %2, %3\n\t"
        "v_cvt_pk_bf16_f32 %1, %4, %5\n\t"
        "s_nop 3"
        : "=&v"(r.u[0]), "=&v"(r.u[1])
        : "v"(A[0]), "v"(A[1]), "v"(A[2]), "v"(A[3]));
    r.u[2] = 0u; r.u[3] = 0u;
    return r.v;
}
// residual + relu, f32 register state
__device__ __forceinline__ void accRelu(f32x4 &S, f32x4 h) {
    S[0] += fmaxf(h[0], 0.f); S[1] += fmaxf(h[1], 0.f);
    S[2] += fmaxf(h[2], 0.f); S[3] += fmaxf(h[3], 0.f);
}

// ---------------------------------------------------------------------------
// Prep (tiny, one-shot): Tbf = bf16(emb@W_s2n * sT)  (100x32)
//   Mbf[lyr][row][64]: SIGMA-PERMUTED k axis — physical col c holds the
//   value for logical u = (c>>5)*32 + ((c&7)>>2)*16 + ((c>>3)&3)*4 + (c&3).
//   rows 0..31 = MsT[w][u], rows 32..47 = MvT[w][u]; logical u>=48 -> 0.
// ---------------------------------------------------------------------------
__global__ void prep_kernel(const float* __restrict__ emb,
                            const float* __restrict__ W_s2n,
                            const float* __restrict__ W1, const float* __restrict__ W2,
                            const float* __restrict__ W3, const float* __restrict__ W4,
                            const float* __restrict__ Ws, const float* __restrict__ Wv,
                            ushort* __restrict__ Tbf, ushort* __restrict__ Mbf)
{
    int idx = blockIdx.x * blockDim.x + threadIdx.x;
    if (idx < 3200) {
        int r = idx >> 5, c = idx & 31;
        float acc = 0.f;
        for (int k = 0; k < 32; ++k) acc += emb[r*32 + k] * W_s2n[k*32 + c];
        Tbf[idx] = f2bf(acc * SCALE_T);
        return;
    }
    idx -= 3200;
    if (idx < 3*48*64) {
        int lyr = idx / 3072, rem = idx % 3072;
        int row = rem >> 6, c = rem & 63;
        // physical col c -> logical u via sigma
        int kc = c >> 5, c5 = c & 31, kq2 = c5 >> 3, e = c5 & 7;
        int u = kc*32 + (e >> 2)*16 + kq2*4 + (e & 3);
        float val = 0.f;
        if (row < 32) {
            int w = row;
            if (u < 32) {
                float a = 0.f;
                for (int k = 0; k < 32; ++k)
                    a += W1[lyr*1024 + u*32 + k] * Ws[lyr*1024 + k*32 + w];
                val = a * SCALE_M1;
            } else if (u < 48) {
                int uu = u - 32; float a = 0.f;
                for (int k = 0; k < 32; ++k)
                    a += W4[lyr*512 + uu*32 + k] * Ws[lyr*1024 + k*32 + w];
                val = a * SCALE_M2;
            }
        } else {
            int w = row - 32;
            if (u < 32) {
                float a = 0.f;
                for (int k = 0; k < 16; ++k)
                    a += W2[lyr*512 + u*16 + k] * Wv[lyr*256 + k*16 + w];
                val = a * SCALE_M34;
            } else if (u < 48) {
                int uu = u - 32; float a = 0.f;
                for (int k = 0; k < 16; ++k)
                    a += W3[lyr*256 + uu*16 + k] * Wv[lyr*256 + k*16 + w];
                val = a * SCALE_M34;
            }
        }
        Mbf[lyr*3072 + row*64 + c] = f2bf(val);
    }
}

// ---------------------------------------------------------------------------
// Fused GNN + MLP: one wave = one graph; 4 graphs/block; 512 blocks.
// Feature state in f32 registers (Ss[2][2], Sv[2][3], D-layout). The
// sigma-permuted k axis makes every A-fragment a pure per-lane cvtpk pack
// of D-tiles — ZERO permlane/LDS in the layer loop (r9 had 84 swaps/layer
// + hazard waits on the critical chain at only 2 waves/SIMD occupancy).
// ---------------------------------------------------------------------------
__global__ __launch_bounds__(256)
void gnn_kernel(const float* __restrict__ pos, const int* __restrict__ z,
                const ushort* __restrict__ Tbf, const ushort* __restrict__ Mbf,
                const float* __restrict__ Wr1, const float* __restrict__ br1,
                const float* __restrict__ Wr2, const float* __restrict__ br2,
                float* __restrict__ out, int B)
{
    __shared__ __align__(16) char smem[26880];
    ushort* featA = (ushort*)smem;                    // 4*80*40*2 = 25600 B
    float*  hgl   = (float*)(smem + 25600);           // 4*80*4    = 1280 B
    float*  h1    = (float*)smem;                     // alias featA (post-layers)
    float*  red   = (float*)(smem + 4096);            // alias featA, after h1

    const int tid = threadIdx.x;
    const int wv = tid >> 6, l = tid & 63;
    const int g  = blockIdx.x*4 + wv;
    ushort* F  = featA + wv*80*FSTR;
    const int ln = l & 15, kq = l >> 4;

    // s init: F[c][n] = Tbf[z[n]][c]  (transposed scatter, wave-private)
    {
        int n = l & 31, h = l >> 5;
        int zg = z[g*32 + n];
        uint4 t0 = *(const uint4*)(Tbf + zg*32 + h*16);
        uint4 t1 = *(const uint4*)(Tbf + zg*32 + h*16 + 8);
        unsigned ua[8] = {t0.x, t0.y, t0.z, t0.w, t1.x, t1.y, t1.z, t1.w};
        #pragma unroll
        for (int q = 0; q < 8; ++q) {
            F[(h*16 + 2*q    )*FSTR + n] = (ushort)ua[q];
            F[(h*16 + 2*q + 1)*FSTR + n] = (ushort)(ua[q] >> 16);
        }
    }

    // register feature state, D-layout: lane=channel, regs=node (mt*16+kq*4+q)
    f32x4 Ss[2][2];            // [node-tile][s-ch-tile]
    f32x4 Sv[2][3];            // [node-tile][spatial i], v-ch = lane
    #pragma unroll
    for (int mt = 0; mt < 2; ++mt) {
        #pragma unroll
        for (int wt = 0; wt < 2; ++wt) {
            uint2 d = *(const uint2*)&F[(wt*16 + ln)*FSTR + mt*16 + kq*4];
            Ss[mt][wt][0] = bf2f((ushort)(d.x      ));
            Ss[mt][wt][1] = bf2f((ushort)(d.x >> 16));
            Ss[mt][wt][2] = bf2f((ushort)(d.y      ));
            Ss[mt][wt][3] = bf2f((ushort)(d.y >> 16));
        }
        #pragma unroll
        for (int i = 0; i < 3; ++i)
            Sv[mt][i] = (f32x4){0.f, 0.f, 0.f, 0.f};
    }

    // adjacency fragments, sigma-permuted k (src = (jj>>2)*16 + kq*4 + (jj&3))
    bf16x8 adjf[4][2];
    {
        #pragma unroll
        for (int nt = 0; nt < 2; ++nt) {
            int ng = g*32 + nt*16 + ln;
            float px = pos[3*ng], py = pos[3*ng+1], pz = pos[3*ng+2];
            union { bf16x8 v; ushort s[8]; } o[4];
            #pragma unroll
            for (int jj = 0; jj < 8; ++jj) {
                int j = g*32 + ((jj >> 2) << 4) + kq*4 + (jj & 3);
                float dx = __fsub_rn(px, pos[3*j]);
                float dy = __fsub_rn(py, pos[3*j+1]);
                float dz = __fsub_rn(pz, pos[3*j+2]);
                float d2 = __fadd_rn(__fadd_rn(__fmul_rn(dx,dx), __fmul_rn(dy,dy)),
                                     __fmul_rn(dz,dz));
                bool on = (d2 <= 25.0f) && (d2 > 0.0f);
                float rinv = on ? rsqrtf(d2) * SQRT3F : 0.f;
                o[0].s[jj] = on ? (ushort)0x3F80 : (ushort)0;   // bf16(1.0)
                o[1].s[jj] = f2bf(dx * rinv);
                o[2].s[jj] = f2bf(dy * rinv);
                o[3].s[jj] = f2bf(dz * rinv);
            }
            #pragma unroll
            for (int w = 0; w < 4; ++w) adjf[w][nt] = o[w].v;
        }
    }

    const f32x4 z4 = {0.f, 0.f, 0.f, 0.f};

    for (int lay = 0; lay < 3; ++lay) {
        const ushort* Mg = Mbf + lay*3072;
        // A-frags from register state: pure cvtpk packs (sigma layout)
        bf16x8 fs0 = frag2(Ss[0][0], Ss[1][0]);
        bf16x8 fs1 = frag2(Ss[0][1], Ss[1][1]);
        bf16x8 fv0 = frag2(Sv[0][0], Sv[1][0]);
        bf16x8 fv1 = frag2(Sv[0][1], Sv[1][1]);
        bf16x8 fv2 = frag2(Sv[0][2], Sv[1][2]);
        // M fragments for this layer (global, L1-hot; sigma baked in by prep)
        bf16x8 bmS0[2], bmS1[2], bmV[2];
        #pragma unroll
        for (int kc = 0; kc < 2; ++kc) {
            bmS0[kc] = *(const bf16x8*)&Mg[(     ln)*64 + kc*32 + kq*8];
            bmS1[kc] = *(const bf16x8*)&Mg[(16 + ln)*64 + kc*32 + kq*8];
            bmV [kc] = *(const bf16x8*)&Mg[(32 + ln)*64 + kc*32 + kq*8];
        }

        bf16x8 agf[2][2];   // [node-tile][k-block] stage-2 A fragments

        // ---- scalar path: agg rows = [A0*s (u<32) | sum_i Ai*v_i (u32..47)]
        #pragma unroll
        for (int nt = 0; nt < 2; ++nt) {
            f32x4 T0 = mfma(fs0, adjf[0][nt], z4);
            f32x4 T1 = mfma(fs1, adjf[0][nt], z4);
            f32x4 T2 = mfma(fv2, adjf[3][nt], z4);
            T2 = mfma(fv1, adjf[2][nt], T2);
            T2 = mfma(fv0, adjf[1][nt], T2);
            agf[nt][0] = frag2(T0, T1);
            agf[nt][1] = frag1z(T2);
        }
        f32x4 hs[2][2] = {{z4, z4}, {z4, z4}};   // [node-tile][w-tile]
        #pragma unroll
        for (int kc = 0; kc < 2; ++kc)
            #pragma unroll
            for (int mt = 0; mt < 2; ++mt) {
                hs[mt][0] = mfma(agf[mt][kc], bmS0[kc], hs[mt][0]);
                hs[mt][1] = mfma(agf[mt][kc], bmS1[kc], hs[mt][1]);
            }
        #pragma unroll
        for (int mt = 0; mt < 2; ++mt)
            #pragma unroll
            for (int wt = 0; wt < 2; ++wt)
                accRelu(Ss[mt][wt], hs[mt][wt]);

        // ---- vector path, one spatial component i at a time
        #pragma unroll
        for (int i = 0; i < 3; ++i) {
            bf16x8 fvi = (i == 0) ? fv0 : (i == 1) ? fv1 : fv2;
            #pragma unroll
            for (int nt = 0; nt < 2; ++nt) {
                f32x4 T0 = mfma(fs0, adjf[1+i][nt], z4);
                f32x4 T1 = mfma(fs1, adjf[1+i][nt], z4);
                f32x4 T2 = mfma(fvi, adjf[0][nt], z4);
                agf[nt][0] = frag2(T0, T1);
                agf[nt][1] = frag1z(T2);
            }
            f32x4 hv[2] = {z4, z4};
            #pragma unroll
            for (int kc = 0; kc < 2; ++kc)
                #pragma unroll
                for (int mt = 0; mt < 2; ++mt)
                    hv[mt] = mfma(agf[mt][kc], bmV[kc], hv[mt]);
            #pragma unroll
            for (int mt = 0; mt < 2; ++mt)
                accRelu(Sv[mt][i], hv[mt]);
        }
    }

    // write state back to F (bf16) for the pooling pass
    #pragma unroll
    for (int mt = 0; mt < 2; ++mt) {
        #pragma unroll
        for (int wt = 0; wt < 2; ++wt) {
            uint2 w;
            w.x = cvtpk(Ss[mt][wt][0], Ss[mt][wt][1]);
            w.y = cvtpk(Ss[mt][wt][2], Ss[mt][wt][3]);
            *(uint2*)&F[(wt*16 + ln)*FSTR + mt*16 + kq*4] = w;
        }
        #pragma unroll
        for (int i = 0; i < 3; ++i) {
            uint2 w;
            w.x = cvtpk(Sv[mt][i][0], Sv[mt][i][1]);
            w.y = cvtpk(Sv[mt][i][2], Sv[mt][i][3]);
            *(uint2*)&F[(32 + i*16 + ln)*FSTR + mt*16 + kq*4] = w;
        }
    }

    // wave-local sum-pool -> hgl[wv][80]
    for (int f = l; f < 80; f += 64) {
        const ushort* row;
        if (f < 32) row = &F[f*FSTR];
        else { int c = f - 32, w = c/3, i = c - 3*w; row = &F[(32 + i*16 + w)*FSTR]; }
        const uint* r32 = (const uint*)row;
        float acc = 0.f;
        #pragma unroll
        for (int q = 0; q < 16; ++q) {
            uint u = r32[q];
            acc += bf2f((ushort)u) + bf2f((ushort)(u >> 16));
        }
        hgl[wv*80 + f] = acc;
    }
    __syncthreads();   // hgl complete; featA (F) dead -> h1/red alias safe

    // --- fused MLP head (block = its 4 graphs) ---
    {
        const int w = tid;
        float acc0 = br1[w];
        float acc1 = acc0, acc2 = acc0, acc3 = acc0;
        #pragma unroll 4
        for (int f = 0; f < 80; ++f) {
            float wvv = Wr1[f*256 + w];
            acc0 = fmaf(hgl[0*80 + f], wvv, acc0);
            acc1 = fmaf(hgl[1*80 + f], wvv, acc1);
            acc2 = fmaf(hgl[2*80 + f], wvv, acc2);
            acc3 = fmaf(hgl[3*80 + f], wvv, acc3);
        }
        h1[0*256 + w] = fmaxf(acc0, 0.f);
        h1[1*256 + w] = fmaxf(acc1, 0.f);
        h1[2*256 + w] = fmaxf(acc2, 0.f);
        h1[3*256 + w] = fmaxf(acc3, 0.f);
    }
    __syncthreads();
    {
        const int g0 = blockIdx.x * 4;
        const int w2 = tid & 127, kh = tid >> 7;
        const float4* h1v = (const float4*)h1;   // [4][64] float4 view
        float s0 = 0.f, s1 = 0.f, s2 = 0.f, s3 = 0.f;
        #pragma unroll 2
        for (int k4 = kh*32; k4 < kh*32 + 32; ++k4) {
            float4 hA = h1v[0*64 + k4];
            float4 hB = h1v[1*64 + k4];
            float4 hC = h1v[2*64 + k4];
            float4 hD = h1v[3*64 + k4];
            int k = k4 * 4;
            float m0 = Wr2[(size_t)(k+0)*128 + w2];
            float m1 = Wr2[(size_t)(k+1)*128 + w2];
            float m2 = Wr2[(size_t)(k+2)*128 + w2];
            float m3 = Wr2[(size_t)(k+3)*128 + w2];
            s0 = fmaf(hA.x,m0, fmaf(hA.y,m1, fmaf(hA.z,m2, fmaf(hA.w,m3, s0))));
            s1 = fmaf(hB.x,m0, fmaf(hB.y,m1, fmaf(hB.z,m2, fmaf(hB.w,m3, s1))));
            s2 = fmaf(hC.x,m0, fmaf(hC.y,m1, fmaf(hC.z,m2, fmaf(hC.w,m3, s2))));
            s3 = fmaf(hD.x,m0, fmaf(hD.y,m1, fmaf(hD.z,m2, fmaf(hD.w,m3, s3))));
        }
        if (kh) {
            red[0*128 + w2] = s0; red[1*128 + w2] = s1;
            red[2*128 + w2] = s2; red[3*128 + w2] = s3;
        }
        __syncthreads();
        if (!kh) {
            float b = br2[w2];
            out[(size_t)(g0+0)*128 + w2] = s0 + red[0*128 + w2] + b;
            out[(size_t)(g0+1)*128 + w2] = s1 + red[1*128 + w2] + b;
            out[(size_t)(g0+2)*128 + w2] = s2 + red[2*128 + w2] + b;
            out[(size_t)(g0+3)*128 + w2] = s3 + red[3*128 + w2] + b;
        }
    }
}

// ---------------------------------------------------------------------------
extern "C" void kernel_launch(void* const* d_in, const int* in_sizes, int n_in,
                              void* d_out, int out_size, void* d_ws, size_t ws_size,
                              hipStream_t stream)
{
    const float* pos   = (const float*)d_in[0];
    const int*   z     = (const int*)d_in[1];
    const float* emb   = (const float*)d_in[5];
    const float* W_s2n = (const float*)d_in[6];
    const float* W1    = (const float*)d_in[7];
    const float* W2    = (const float*)d_in[8];
    const float* W3    = (const float*)d_in[9];
    const float* W4    = (const float*)d_in[10];
    const float* Ws    = (const float*)d_in[11];
    const float* Wv    = (const float*)d_in[12];
    const float* Wr1   = (const float*)d_in[13];
    const float* br1   = (const float*)d_in[14];
    const float* Wr2   = (const float*)d_in[15];
    const float* br2   = (const float*)d_in[16];
    float* out = (float*)d_out;

    const int B = out_size / 128;      // graphs (2048)

    // workspace: Tbf (3200 shorts) | Mbf (9216 shorts)
    char* p = (char*)d_ws;
    ushort* Tbf = (ushort*)p;  p += 6400;
    ushort* Mbf = (ushort*)p;  p += 18432;

    const int prep_total = 3200 + 3*48*64;
    prep_kernel<<<(prep_total + 255) / 256, 256, 0, stream>>>(
        emb, W_s2n, W1, W2, W3, W4, Ws, Wv, Tbf, Mbf);

    gnn_kernel<<<B / 4, 256, 0, stream>>>(pos, z, Tbf, Mbf,
                                          Wr1, br1, Wr2, br2, out, B);
}